// Round 1
// baseline (14097.391 us; speedup 1.0000x reference)
//
#include <hip/hip_runtime.h>

// WeatherModel: ConvLSTM encoder-decoder with attention, fp32 baseline.
// B=4, T_IN=10, T_OUT=5, D=5, M=N=96, H1=64, ATTN=32, SEL=0.

#define PIX  9216      // 96*96
#define MN   96
#define NB   4
#define TIN  10
#define TOUT 5
#define ND   5
#define HID  64

__device__ __forceinline__ float sigmf_(float x) { return 1.0f / (1.0f + __expf(-x)); }
__device__ __forceinline__ float tanhf_(float x) { return 1.0f - 2.0f / (__expf(2.0f * x) + 1.0f); }

// ---------------------------------------------------------------------------
// Big ConvLSTM cell: hidden=64.  Tile 16x4 pixels, 16 hidden ch per block.
// Input = concat(x [CINX_D ch], hprev [64 ch]); weights have CINX_W + 64 cin.
// (CINX_D=0, CINX_W=1 for decoder layer0 whose x input is all-zeros.)
// c updated in place (per-element), h must ping-pong (3x3 halo reads).
// ---------------------------------------------------------------------------
template <int CINX_D, int CINX_W>
__global__ void __launch_bounds__(256)
cell64_kernel(const float* __restrict__ xin, int xin_bstride,
              const float* __restrict__ hprev, const float* cprev,
              const float* __restrict__ w, const float* __restrict__ bias,
              float* __restrict__ hout, float* cout)
{
    constexpr int CIN_TOT = CINX_D + HID;
    constexpr int WCIN = CINX_W + HID;
    __shared__ float patch[64 * 108];              // [cin chunk][6 rows][18 cols]

    const int tx = threadIdx.x;                    // 0..15 (pixel x)
    const int hcIdx = threadIdx.y;                 // 0..15 (hidden ch in group)
    const int tid = hcIdx * 16 + tx;
    const int x0 = blockIdx.x * 16;
    const int y0 = blockIdx.y * 4;
    const int bz = blockIdx.z;                     // b*4 + hcGroup
    const int bb = bz >> 2;
    const int hc = (bz & 3) * 16 + hcIdx;

    float acc[4][4] = {};                          // [gate][pixel row]

    for (int cbase = 0; cbase < CIN_TOT; cbase += 64) {
        const int cnum = (CIN_TOT - cbase < 64) ? (CIN_TOT - cbase) : 64;
        // stage input patch (with zero padding) for this cin chunk
        for (int idx = tid; idx < cnum * 108; idx += 256) {
            int ci = idx / 108;
            int rem = idx - ci * 108;
            int r = rem / 18;
            int cc = rem - r * 18;
            int cin = cbase + ci;
            int gy = y0 - 1 + r, gx = x0 - 1 + cc;
            float v = 0.0f;
            if ((unsigned)gy < 96u && (unsigned)gx < 96u) {
                if (cin < CINX_D)
                    v = xin[bb * xin_bstride + (cin * 96 + gy) * 96 + gx];
                else
                    v = hprev[((bb * HID + (cin - CINX_D)) * 96 + gy) * 96 + gx];
            }
            patch[idx] = v;
        }
        __syncthreads();

        for (int ci = 0; ci < cnum; ++ci) {
            const int cin = cbase + ci;
            float pv[6][3];
            const float* pp = patch + ci * 108 + tx;
#pragma unroll
            for (int r = 0; r < 6; ++r) {
                pv[r][0] = pp[r * 18 + 0];
                pv[r][1] = pp[r * 18 + 1];
                pv[r][2] = pp[r * 18 + 2];
            }
            const int wcin = (CINX_D == CINX_W) ? cin
                             : (cin < CINX_D ? cin : cin + (CINX_W - CINX_D));
#pragma unroll
            for (int g = 0; g < 4; ++g) {
                const float* wp = w + ((g * HID + hc) * WCIN + wcin) * 9;
                float wr[9];
#pragma unroll
                for (int k = 0; k < 9; ++k) wr[k] = wp[k];
#pragma unroll
                for (int p = 0; p < 4; ++p) {
                    float s = acc[g][p];
                    s = fmaf(wr[0], pv[p + 0][0], s);
                    s = fmaf(wr[1], pv[p + 0][1], s);
                    s = fmaf(wr[2], pv[p + 0][2], s);
                    s = fmaf(wr[3], pv[p + 1][0], s);
                    s = fmaf(wr[4], pv[p + 1][1], s);
                    s = fmaf(wr[5], pv[p + 1][2], s);
                    s = fmaf(wr[6], pv[p + 2][0], s);
                    s = fmaf(wr[7], pv[p + 2][1], s);
                    s = fmaf(wr[8], pv[p + 2][2], s);
                    acc[g][p] = s;
                }
            }
        }
        __syncthreads();
    }

    const float bi = bias[hc], bf = bias[HID + hc];
    const float bo = bias[2 * HID + hc], bg = bias[3 * HID + hc];
#pragma unroll
    for (int p = 0; p < 4; ++p) {
        int y = y0 + p;
        int idx = ((bb * HID + hc) * 96 + y) * 96 + x0 + tx;
        float ii = sigmf_(acc[0][p] + bi);
        float ff = sigmf_(acc[1][p] + bf);
        float oo = sigmf_(acc[2][p] + bo);
        float gg = tanhf_(acc[3][p] + bg);
        float cn = ff * cprev[idx] + ii * gg;
        cout[idx] = cn;
        hout[idx] = oo * tanhf_(cn);
    }
}

// ---------------------------------------------------------------------------
// Small ConvLSTM cell (hidden=1): gates kernel (thread per pixel*gate) + update
// ---------------------------------------------------------------------------
template <int CINX>
__global__ void gates1_kernel(const float* __restrict__ xin, int xin_bstride,
                              const float* __restrict__ hprev,
                              const float* __restrict__ w, const float* __restrict__ bias,
                              float* __restrict__ z)
{
    int p = blockIdx.x * 256 + threadIdx.x;
    int g = blockIdx.y, bb = blockIdx.z;
    int y = p / 96, x = p - y * 96;
    float acc = bias[g];
    for (int cin = 0; cin <= CINX; ++cin) {
        const float* src = (cin < CINX) ? (xin + bb * xin_bstride + cin * PIX)
                                        : (hprev + bb * PIX);
        const float* wp = w + (g * (CINX + 1) + cin) * 9;
#pragma unroll
        for (int ky = 0; ky < 3; ++ky) {
            int gy = y + ky - 1;
            if ((unsigned)gy >= 96u) continue;
#pragma unroll
            for (int kx = 0; kx < 3; ++kx) {
                int gx = x + kx - 1;
                if ((unsigned)gx >= 96u) continue;
                acc = fmaf(wp[ky * 3 + kx], src[gy * 96 + gx], acc);
            }
        }
    }
    z[(bb * 4 + g) * PIX + p] = acc;
}

__global__ void update1_kernel(const float* __restrict__ z, const float* cprev,
                               float* __restrict__ hout, float* cout)
{
    int p = blockIdx.x * 256 + threadIdx.x;
    int bb = blockIdx.y;
    float zi = z[(bb * 4 + 0) * PIX + p], zf = z[(bb * 4 + 1) * PIX + p];
    float zo = z[(bb * 4 + 2) * PIX + p], zg = z[(bb * 4 + 3) * PIX + p];
    int idx = bb * PIX + p;
    float cn = sigmf_(zf) * cprev[idx] + sigmf_(zi) * tanhf_(zg);
    cout[idx] = cn;
    hout[idx] = sigmf_(zo) * tanhf_(cn);
}

// ---------------------------------------------------------------------------
// Attention
// ---------------------------------------------------------------------------
__global__ void hid_e_kernel(const float* __restrict__ h, const float* __restrict__ c,
                             const float* __restrict__ wh, const float* __restrict__ bh,
                             float* __restrict__ out)
{
    int p = blockIdx.x * 256 + threadIdx.x;
    int oc = blockIdx.y, bb = blockIdx.z;
    int y = p / 96, x = p - y * 96;
    float acc = bh[oc];
#pragma unroll
    for (int cin = 0; cin < 2; ++cin) {
        const float* src = (cin == 0 ? h : c) + bb * PIX;
        const float* wp = wh + (oc * 2 + cin) * 9;
#pragma unroll
        for (int ky = 0; ky < 3; ++ky) {
            int gy = y + ky - 1;
            if ((unsigned)gy >= 96u) continue;
#pragma unroll
            for (int kx = 0; kx < 3; ++kx) {
                int gx = x + kx - 1;
                if ((unsigned)gx >= 96u) continue;
                acc = fmaf(wp[ky * 3 + kx], src[gy * 96 + gx], acc);
            }
        }
    }
    out[(bb * 32 + oc) * PIX + p] = acc;
}

__global__ void attn_e_kernel(const float* __restrict__ xs, int k,
                              const float* __restrict__ wi, const float* __restrict__ bi,
                              const float* __restrict__ hidE, float* __restrict__ e)
{
    int p = blockIdx.x * 256 + threadIdx.x;
    int oc = blockIdx.y, bb = blockIdx.z;
    int y = p / 96, x = p - y * 96;
    float acc = bi[oc];
    for (int t = 0; t < TIN; ++t) {
        const float* src = xs + ((bb * TIN + t) * ND + k) * PIX;
        const float* wp = wi + (oc * TIN + t) * 9;
#pragma unroll
        for (int ky = 0; ky < 3; ++ky) {
            int gy = y + ky - 1;
            if ((unsigned)gy >= 96u) continue;
#pragma unroll
            for (int kx = 0; kx < 3; ++kx) {
                int gx = x + kx - 1;
                if ((unsigned)gx >= 96u) continue;
                acc = fmaf(wp[ky * 3 + kx], src[gy * 96 + gx], acc);
            }
        }
    }
    int o = (bb * 32 + oc) * PIX + p;
    e[o] = tanhf_(acc + hidE[o]);
}

__global__ void attn_alpha_kernel(const float* __restrict__ e,
                                  const float* __restrict__ wv, const float* __restrict__ bv,
                                  float* __restrict__ alpha, int k)
{
    int p = blockIdx.x * 256 + threadIdx.x;
    int bb = blockIdx.y;
    int y = p / 96, x = p - y * 96;
    float acc = bv[0];
    for (int cin = 0; cin < 32; ++cin) {
        const float* src = e + (bb * 32 + cin) * PIX;
        const float* wp = wv + cin * 9;
#pragma unroll
        for (int ky = 0; ky < 3; ++ky) {
            int gy = y + ky - 1;
            if ((unsigned)gy >= 96u) continue;
#pragma unroll
            for (int kx = 0; kx < 3; ++kx) {
                int gx = x + kx - 1;
                if ((unsigned)gx >= 96u) continue;
                acc = fmaf(wp[ky * 3 + kx], src[gy * 96 + gx], acc);
            }
        }
    }
    alpha[(bb * ND + k) * PIX + p] = acc;
}

__global__ void redmax1_kernel(const float* __restrict__ a, int n, float* __restrict__ partial)
{
    __shared__ float s[256];
    float m = -1e30f;
    for (int i = blockIdx.x * 256 + threadIdx.x; i < n; i += gridDim.x * 256)
        m = fmaxf(m, a[i]);
    s[threadIdx.x] = m;
    __syncthreads();
    for (int st = 128; st > 0; st >>= 1) {
        if (threadIdx.x < st) s[threadIdx.x] = fmaxf(s[threadIdx.x], s[threadIdx.x + st]);
        __syncthreads();
    }
    if (threadIdx.x == 0) partial[blockIdx.x] = s[0];
}

__global__ void redmax2_kernel(const float* __restrict__ partial, int n, float* __restrict__ out)
{
    __shared__ float s[256];
    float m = (threadIdx.x < n) ? partial[threadIdx.x] : -1e30f;
    s[threadIdx.x] = m;
    __syncthreads();
    for (int st = 128; st > 0; st >>= 1) {
        if (threadIdx.x < st) s[threadIdx.x] = fmaxf(s[threadIdx.x], s[threadIdx.x + st]);
        __syncthreads();
    }
    if (threadIdx.x == 0) out[0] = s[0];
}

// xs[b,t,d,:,:] *= exp(alpha[b,d,:,:] - max)   (broadcast over t)
__global__ void scale_xs_kernel(float* __restrict__ xs, const float* __restrict__ alpha,
                                const float* __restrict__ mval)
{
    int idx = blockIdx.x * 256 + threadIdx.x;      // < 1,843,200
    int p = idx % PIX;
    int q = idx / PIX;
    int d = q % ND;
    int bb = (q / ND) / TIN;
    float wgt = __expf(alpha[(bb * ND + d) * PIX + p] - mval[0]);
    xs[idx] *= wgt;
}

// ---------------------------------------------------------------------------
// Decoder output head + misc
// ---------------------------------------------------------------------------
__global__ void tcnn_kernel(const float* __restrict__ yprev, const float* __restrict__ hl,
                            const float* __restrict__ tw, const float* __restrict__ tb,
                            float* __restrict__ ynext, float* __restrict__ hcarry,
                            float* __restrict__ outp)
{
    int p = blockIdx.x * 256 + threadIdx.x;
    int bb = blockIdx.y;
    float acc = tb[0];
#pragma unroll
    for (int cc = 0; cc < TIN; ++cc)
        acc = fmaf(tw[cc], yprev[(bb * TIN + cc) * PIX + p], acc);
    float hv = hl[bb * PIX + p];
    acc = fmaf(tw[TIN], hv, acc);
    float o = fmaxf(acc, 0.0f);
    outp[bb * TOUT * PIX + p] = o;
#pragma unroll
    for (int cc = 0; cc < TIN - 1; ++cc)
        ynext[(bb * TIN + cc) * PIX + p] = yprev[(bb * TIN + cc + 1) * PIX + p];
    ynext[(bb * TIN + 9) * PIX + p] = hv;
    hcarry[bb * PIX + p] = o;
}

__global__ void slice_y_kernel(const float* __restrict__ x, float* __restrict__ yp)
{
    int idx = blockIdx.x * 256 + threadIdx.x;      // < 368,640
    int p = idx % PIX;
    int q = idx / PIX;                             // bb*10 + t
    yp[idx] = x[(q * ND + 0) * PIX + p];           // SEL = 0
}

// ---------------------------------------------------------------------------
extern "C" void kernel_launch(void* const* d_in, const int* in_sizes, int n_in,
                              void* d_out, int out_size, void* d_ws, size_t ws_size,
                              hipStream_t stream)
{
    const float* x       = (const float*)d_in[0];
    const float* enc_w0  = (const float*)d_in[1];
    const float* enc_b0  = (const float*)d_in[2];
    const float* enc_w1  = (const float*)d_in[3];
    const float* enc_b1  = (const float*)d_in[4];
    const float* enc_w2  = (const float*)d_in[5];
    const float* enc_b2  = (const float*)d_in[6];
    const float* dec_w0  = (const float*)d_in[7];
    const float* dec_b0  = (const float*)d_in[8];
    const float* dec_w1  = (const float*)d_in[9];
    const float* dec_b1  = (const float*)d_in[10];
    const float* dec_w2  = (const float*)d_in[11];
    const float* dec_b2  = (const float*)d_in[12];
    const float* attn_wi = (const float*)d_in[13];
    const float* attn_bi = (const float*)d_in[14];
    const float* attn_wh = (const float*)d_in[15];
    const float* attn_bh = (const float*)d_in[16];
    const float* attn_wv = (const float*)d_in[17];
    const float* attn_bv = (const float*)d_in[18];
    const float* tcnn_w  = (const float*)d_in[19];
    const float* tcnn_b  = (const float*)d_in[20];
    float* out = (float*)d_out;

    float* ws = (float*)d_ws;
    float* xs    = ws; ws += NB * TIN * ND * PIX;   // 1,843,200
    float* h0a   = ws; ws += NB * PIX;
    float* h0b   = ws; ws += NB * PIX;
    float* c0    = ws; ws += NB * PIX;
    float* hl    = ws; ws += NB * PIX;
    float* h1a   = ws; ws += NB * HID * PIX;
    float* h1b   = ws; ws += NB * HID * PIX;
    float* c1    = ws; ws += NB * HID * PIX;
    float* h2a   = ws; ws += NB * HID * PIX;
    float* h2b   = ws; ws += NB * HID * PIX;
    float* c2    = ws; ws += NB * HID * PIX;
    float* hidE  = ws; ws += NB * 32 * PIX;
    float* ebuf  = ws; ws += NB * 32 * PIX;
    float* alpha = ws; ws += NB * ND * PIX;
    float* zbuf  = ws; ws += NB * 4 * PIX;
    float* ypa   = ws; ws += NB * TIN * PIX;
    float* ypb   = ws; ws += NB * TIN * PIX;
    float* partial = ws; ws += 256;
    float* mval  = ws; ws += 1;

    hipMemcpyAsync(xs, x, (size_t)NB * TIN * ND * PIX * sizeof(float),
                   hipMemcpyDeviceToDevice, stream);
    hipMemsetAsync(h0a, 0, NB * PIX * sizeof(float), stream);
    hipMemsetAsync(c0,  0, NB * PIX * sizeof(float), stream);
    hipMemsetAsync(h1a, 0, NB * HID * PIX * sizeof(float), stream);
    hipMemsetAsync(c1,  0, NB * HID * PIX * sizeof(float), stream);
    hipMemsetAsync(h2a, 0, NB * HID * PIX * sizeof(float), stream);
    hipMemsetAsync(c2,  0, NB * HID * PIX * sizeof(float), stream);
    slice_y_kernel<<<dim3(1440), dim3(256), 0, stream>>>(x, ypa);

    float *h0 = h0a, *h0n = h0b, *h1 = h1a, *h1n = h1b, *h2 = h2a, *h2n = h2b;
    dim3 big_grid(6, 24, 16), big_block(16, 16);

    // ---------------- encoder ----------------
    for (int t = 0; t < TIN; ++t) {
        hid_e_kernel<<<dim3(36, 32, NB), 256, 0, stream>>>(h0, c0, attn_wh, attn_bh, hidE);
        for (int k = 0; k < ND; ++k) {
            attn_e_kernel<<<dim3(36, 32, NB), 256, 0, stream>>>(xs, k, attn_wi, attn_bi, hidE, ebuf);
            attn_alpha_kernel<<<dim3(36, NB), 256, 0, stream>>>(ebuf, attn_wv, attn_bv, alpha, k);
        }
        redmax1_kernel<<<dim3(144), 256, 0, stream>>>(alpha, NB * ND * PIX, partial);
        redmax2_kernel<<<dim3(1), 256, 0, stream>>>(partial, 144, mval);
        scale_xs_kernel<<<dim3(7200), 256, 0, stream>>>(xs, alpha, mval);

        gates1_kernel<5><<<dim3(36, 4, NB), 256, 0, stream>>>(xs + t * ND * PIX, TIN * ND * PIX,
                                                              h0, enc_w0, enc_b0, zbuf);
        update1_kernel<<<dim3(36, NB), 256, 0, stream>>>(zbuf, c0, h0n, c0);
        { float* tmp = h0; h0 = h0n; h0n = tmp; }

        cell64_kernel<1, 1><<<big_grid, big_block, 0, stream>>>(h0, PIX, h1, c1,
                                                                enc_w1, enc_b1, h1n, c1);
        { float* tmp = h1; h1 = h1n; h1n = tmp; }

        cell64_kernel<64, 64><<<big_grid, big_block, 0, stream>>>(h1, HID * PIX, h2, c2,
                                                                  enc_w2, enc_b2, h2n, c2);
        { float* tmp = h2; h2 = h2n; h2n = tmp; }
    }

    // ---------------- decoder ----------------
    float *yp = ypa, *ypn = ypb, *hc = h0, *hcn = h0n;
    for (int t = 0; t < TOUT; ++t) {
        cell64_kernel<0, 1><<<big_grid, big_block, 0, stream>>>(nullptr, 0, h2, c2,
                                                                dec_w0, dec_b0, h2n, c2);
        { float* tmp = h2; h2 = h2n; h2n = tmp; }

        cell64_kernel<64, 64><<<big_grid, big_block, 0, stream>>>(h2, HID * PIX, h1, c1,
                                                                  dec_w1, dec_b1, h1n, c1);
        { float* tmp = h1; h1 = h1n; h1n = tmp; }

        gates1_kernel<64><<<dim3(36, 4, NB), 256, 0, stream>>>(h1, HID * PIX, hc,
                                                               dec_w2, dec_b2, zbuf);
        update1_kernel<<<dim3(36, NB), 256, 0, stream>>>(zbuf, c0, hl, c0);
        tcnn_kernel<<<dim3(36, NB), 256, 0, stream>>>(yp, hl, tcnn_w, tcnn_b, ypn, hcn,
                                                      out + t * PIX);
        { float* tmp = yp; yp = ypn; ypn = tmp; }
        { float* tmp = hc; hc = hcn; hcn = tmp; }
    }
}

// Round 2
// 10183.694 us; speedup vs baseline: 1.3843x; 1.3843x over previous
//
#include <hip/hip_runtime.h>

// WeatherModel: ConvLSTM encoder-decoder with attention.
// Big ConvLSTM cells via bf16 MFMA implicit GEMM; rest fp32.
// B=4, T_IN=10, T_OUT=5, D=5, M=N=96, H1=64, ATTN=32, SEL=0.

#define PIX  9216
#define NB   4
#define TIN  10
#define TOUT 5
#define ND   5
#define HID  64

typedef __attribute__((ext_vector_type(8))) short bf16x8;
typedef __attribute__((ext_vector_type(4))) float f32x4;

__device__ __forceinline__ float sigmf_(float x) { return 1.0f / (1.0f + __expf(-x)); }
__device__ __forceinline__ float tanhf_(float x) { return 1.0f - 2.0f / (__expf(2.0f * x) + 1.0f); }
__device__ __forceinline__ unsigned short f2bf(float f) {
    unsigned u = __float_as_uint(f);
    unsigned r = u + 0x7FFFu + ((u >> 16) & 1u);
    return (unsigned short)(r >> 16);
}
__device__ __forceinline__ float bf2f(unsigned short u) {
    return __uint_as_float(((unsigned)u) << 16);
}

// ---------------------------------------------------------------------------
// Big ConvLSTM cell, implicit-GEMM MFMA.
// Packed input  inP[b][NCG=NCH*4][9216][8] bf16 (channel-major groups of 8).
// Packed weight wP[tap 9][NCH][256 oc][32 cin] bf16 (same channel order).
// Output h written as bf16 into up to two packed dest buffers (+ c fp32 inplace).
// Block: 256 thr = 4 waves; wave w = gate w (64 outch); px tile = 48 (half row).
// Grid: (2, 96, NB) = 768 blocks = 3/CU.
// ---------------------------------------------------------------------------
template <int NCH>
__global__ void __launch_bounds__(256, 3)
cell64_mfma(const unsigned short* __restrict__ inP,
            const unsigned short* __restrict__ wP,
            const float* __restrict__ bias,
            const float* cprev, float* cout,
            unsigned short* __restrict__ d1, int d1_coff, int d1_ncg,
            unsigned short* __restrict__ d2, int d2_coff, int d2_ncg)
{
    __shared__ __align__(16) char smem[49152];   // staging 9600B / zbuf 48KB (union)
    const int lane = threadIdx.x;                // 0..63
    const int wv   = threadIdx.y;                // 0..3  (gate)
    const int tid  = wv * 64 + lane;
    const int xh = blockIdx.x, y = blockIdx.y, b = blockIdx.z;
    const int x0 = xh * 48;
    const int l15 = lane & 15, l4 = lane >> 4;
    const int NCG = NCH * 4;

    f32x4 acc[4][3] = {};                        // [oc frag][px frag]

    for (int cc = 0; cc < NCH; ++cc) {
        // stage 3 rows x 50 px x 32 cin (bf16, 16B granules, XOR-swizzled)
        for (int g = tid; g < 600; g += 256) {
            int pr = g >> 2;                     // r*50 + p
            int cg = g & 3;
            int r = pr / 50;
            int p = pr - r * 50;
            int gy = y - 1 + r, gx = x0 - 1 + p;
            uint4 v = make_uint4(0u, 0u, 0u, 0u);
            if ((unsigned)gy < 96u && (unsigned)gx < 96u)
                v = *(const uint4*)(inP + (((size_t)(b * NCG + cc * 4 + cg) * 9216
                                            + gy * 96 + gx) << 3));
            int slot = cg ^ ((p >> 1) & 3);
            *(uint4*)(smem + pr * 64 + slot * 16) = v;
        }
        __syncthreads();

#pragma unroll
        for (int ky = 0; ky < 3; ++ky) {
#pragma unroll
            for (int kx = 0; kx < 3; ++kx) {
                const int tap = ky * 3 + kx;
                const bf16x8* ap = (const bf16x8*)(wP
                    + ((size_t)(tap * NCH + cc) * 256 + wv * 64 + l15) * 32 + l4 * 8);
                bf16x8 af[4];
                af[0] = ap[0]; af[1] = ap[64]; af[2] = ap[128]; af[3] = ap[192];
                bf16x8 bk[3];
#pragma unroll
                for (int k = 0; k < 3; ++k) {
                    int p = k * 16 + kx + l15;
                    int slot = l4 ^ ((p >> 1) & 3);
                    bk[k] = *(const bf16x8*)(smem + (ky * 50 + p) * 64 + slot * 16);
                }
#pragma unroll
                for (int f = 0; f < 4; ++f)
#pragma unroll
                    for (int k = 0; k < 3; ++k)
                        acc[f][k] = __builtin_amdgcn_mfma_f32_16x16x32_bf16(
                            af[f], bk[k], acc[f][k], 0, 0, 0);
            }
        }
        __syncthreads();
    }

    // gate exchange through LDS: zbuf[gate][64 hc][48 px] f32
    float* zb = (float*)smem;
#pragma unroll
    for (int f = 0; f < 4; ++f)
#pragma unroll
        for (int k = 0; k < 3; ++k)
#pragma unroll
            for (int r = 0; r < 4; ++r) {
                int hc = f * 16 + l4 * 4 + r;
                int px = k * 16 + l15;
                zb[(wv * 64 + hc) * 48 + px] = acc[f][k][r];
            }
    __syncthreads();

    for (int i = 0; i < 12; ++i) {
        int e = i * 256 + tid;                   // 0..3071
        int hc = e / 48, px = e - hc * 48;
        float zi = zb[(0 * 64 + hc) * 48 + px];
        float zf = zb[(1 * 64 + hc) * 48 + px];
        float zo = zb[(2 * 64 + hc) * 48 + px];
        float zg = zb[(3 * 64 + hc) * 48 + px];
        float ii = sigmf_(zi + bias[hc]);
        float ff = sigmf_(zf + bias[64 + hc]);
        float oo = sigmf_(zo + bias[128 + hc]);
        float gg = tanhf_(zg + bias[192 + hc]);
        int gpix = y * 96 + x0 + px;
        int cidx = (b * HID + hc) * 9216 + gpix;
        float cn = ff * cprev[cidx] + ii * gg;
        cout[cidx] = cn;
        unsigned short hb = f2bf(oo * tanhf_(cn));
        int ch1 = d1_coff + hc;
        d1[((size_t)(b * d1_ncg + (ch1 >> 3)) * 9216 + gpix) * 8 + (ch1 & 7)] = hb;
        if (d2) {
            int ch2 = d2_coff + hc;
            d2[((size_t)(b * d2_ncg + (ch2 >> 3)) * 9216 + gpix) * 8 + (ch2 & 7)] = hb;
        }
    }
}

// pack conv weights [oc][WCIN][3][3] fp32 -> [tap][NCH][256][32] bf16
__global__ void wpack_kernel(const float* __restrict__ w, unsigned short* __restrict__ wp,
                             int WCIN, int NCH, int coff, int climit)
{
    int idx = blockIdx.x * 256 + threadIdx.x;
    int total = 9 * NCH * 256 * 32;
    if (idx >= total) return;
    int k = idx & 31;
    int oc = (idx >> 5) & 255;
    int rest = idx >> 13;                        // tap*NCH + cc
    int cc = rest % NCH, tap = rest / NCH;
    int c = cc * 32 + k;
    float v = 0.0f;
    if (c < climit) v = w[(oc * WCIN + (c + coff)) * 9 + tap];
    wp[idx] = f2bf(v);
}

// ---------------------------------------------------------------------------
// Small ConvLSTM cells (hidden=1), gates+update fused.
// ---------------------------------------------------------------------------
__global__ void small_cell5(const float* __restrict__ xs_t,   // xs + t*ND*PIX
                            const float* __restrict__ hprev, const float* cprev,
                            const float* __restrict__ w, const float* __restrict__ bias,
                            float* __restrict__ hout, float* cout,
                            unsigned short* __restrict__ pk, int ncg)
{
    int p = blockIdx.x * 256 + threadIdx.x;
    int bb = blockIdx.y;
    int y = p / 96, x = p - y * 96;
    float acc[4] = { bias[0], bias[1], bias[2], bias[3] };
    for (int cin = 0; cin < 6; ++cin) {
        const float* src = (cin < 5) ? (xs_t + (bb * TIN * ND + cin) * PIX)
                                     : (hprev + bb * PIX);
#pragma unroll
        for (int ky = 0; ky < 3; ++ky) {
            int gy = y + ky - 1;
            if ((unsigned)gy >= 96u) continue;
#pragma unroll
            for (int kx = 0; kx < 3; ++kx) {
                int gx = x + kx - 1;
                if ((unsigned)gx >= 96u) continue;
                float v = src[gy * 96 + gx];
#pragma unroll
                for (int g = 0; g < 4; ++g)
                    acc[g] = fmaf(w[(g * 6 + cin) * 9 + ky * 3 + kx], v, acc[g]);
            }
        }
    }
    int idx = bb * PIX + p;
    float cn = sigmf_(acc[1]) * cprev[idx] + sigmf_(acc[0]) * tanhf_(acc[3]);
    cout[idx] = cn;
    float h = sigmf_(acc[2]) * tanhf_(cn);
    hout[idx] = h;
    pk[((size_t)(bb * ncg) * 9216 + p) * 8] = f2bf(h);   // packed channel 0
}

__global__ void small_cell64(const unsigned short* __restrict__ xin, int ncg, int cbase,
                             const float* __restrict__ hprev, const float* cprev,
                             const float* __restrict__ w, const float* __restrict__ bias,
                             float* __restrict__ hout, float* cout)
{
    int p = blockIdx.x * 256 + threadIdx.x;
    int bb = blockIdx.y;
    int y = p / 96, x = p - y * 96;
    float acc[4] = { bias[0], bias[1], bias[2], bias[3] };
    for (int cin = 0; cin < 65; ++cin) {
#pragma unroll
        for (int ky = 0; ky < 3; ++ky) {
            int gy = y + ky - 1;
            if ((unsigned)gy >= 96u) continue;
#pragma unroll
            for (int kx = 0; kx < 3; ++kx) {
                int gx = x + kx - 1;
                if ((unsigned)gx >= 96u) continue;
                float v;
                if (cin < 64) {
                    int ch = cbase + cin;
                    v = bf2f(xin[((size_t)(bb * ncg + (ch >> 3)) * 9216
                                  + gy * 96 + gx) * 8 + (ch & 7)]);
                } else {
                    v = hprev[bb * PIX + gy * 96 + gx];
                }
#pragma unroll
                for (int g = 0; g < 4; ++g)
                    acc[g] = fmaf(w[(g * 65 + cin) * 9 + ky * 3 + kx], v, acc[g]);
            }
        }
    }
    int idx = bb * PIX + p;
    float cn = sigmf_(acc[1]) * cprev[idx] + sigmf_(acc[0]) * tanhf_(acc[3]);
    cout[idx] = cn;
    hout[idx] = sigmf_(acc[2]) * tanhf_(cn);
}

// ---------------------------------------------------------------------------
// Fused attention: per (y, k, b) block computes e (32ch x 3rows x 98px, in LDS)
// then alpha for row y.  alpha[(b*5+k)][pix].
// ---------------------------------------------------------------------------
__global__ void __launch_bounds__(256)
attn_fused(const float* __restrict__ xs, const float* __restrict__ h0,
           const float* __restrict__ c0,
           const float* __restrict__ wi, const float* __restrict__ bi,
           const float* __restrict__ wh, const float* __restrict__ bh,
           const float* __restrict__ wv, const float* __restrict__ bv,
           float* __restrict__ alpha)
{
    __shared__ float eld[32 * 3 * 98];
    const int y = blockIdx.x, k = blockIdx.y, bb = blockIdx.z;
    const int tid = threadIdx.x;

    for (int v = tid; v < 32 * 294; v += 256) {
        int ch = v / 294;
        int rem = v - ch * 294;
        int r = rem / 98, p = rem - r * 98;
        int gy = y - 1 + r, gx = p - 1;
        float e = 0.0f;
        if ((unsigned)gy < 96u && (unsigned)gx < 96u) {
            float acc = bi[ch] + bh[ch];
            for (int t = 0; t < TIN; ++t) {
                const float* src = xs + ((size_t)(bb * TIN + t) * ND + k) * PIX;
                const float* wp = wi + (ch * TIN + t) * 9;
#pragma unroll
                for (int ky = 0; ky < 3; ++ky) {
                    int iy = gy + ky - 1;
                    if ((unsigned)iy >= 96u) continue;
#pragma unroll
                    for (int kx = 0; kx < 3; ++kx) {
                        int ix = gx + kx - 1;
                        if ((unsigned)ix >= 96u) continue;
                        acc = fmaf(wp[ky * 3 + kx], src[iy * 96 + ix], acc);
                    }
                }
            }
#pragma unroll
            for (int cin = 0; cin < 2; ++cin) {
                const float* src = (cin == 0 ? h0 : c0) + bb * PIX;
                const float* wp = wh + (ch * 2 + cin) * 9;
#pragma unroll
                for (int ky = 0; ky < 3; ++ky) {
                    int iy = gy + ky - 1;
                    if ((unsigned)iy >= 96u) continue;
#pragma unroll
                    for (int kx = 0; kx < 3; ++kx) {
                        int ix = gx + kx - 1;
                        if ((unsigned)ix >= 96u) continue;
                        acc = fmaf(wp[ky * 3 + kx], src[iy * 96 + ix], acc);
                    }
                }
            }
            e = tanhf_(acc);
        }
        eld[v] = e;
    }
    __syncthreads();

    if (tid < 96) {
        float acc = bv[0];
        for (int ch = 0; ch < 32; ++ch) {
            const float* wp = wv + ch * 9;
#pragma unroll
            for (int r = 0; r < 3; ++r)
#pragma unroll
                for (int dx = 0; dx < 3; ++dx)
                    acc = fmaf(wp[r * 3 + dx], eld[(ch * 3 + r) * 98 + tid + dx], acc);
        }
        alpha[(size_t)(bb * ND + k) * PIX + y * 96 + tid] = acc;
    }
}

__global__ void redmax1_kernel(const float* __restrict__ a, int n, float* __restrict__ partial)
{
    __shared__ float s[256];
    float m = -1e30f;
    for (int i = blockIdx.x * 256 + threadIdx.x; i < n; i += gridDim.x * 256)
        m = fmaxf(m, a[i]);
    s[threadIdx.x] = m;
    __syncthreads();
    for (int st = 128; st > 0; st >>= 1) {
        if (threadIdx.x < st) s[threadIdx.x] = fmaxf(s[threadIdx.x], s[threadIdx.x + st]);
        __syncthreads();
    }
    if (threadIdx.x == 0) partial[blockIdx.x] = s[0];
}

__global__ void redmax2_kernel(const float* __restrict__ partial, int n, float* __restrict__ out)
{
    __shared__ float s[256];
    float m = (threadIdx.x < n) ? partial[threadIdx.x] : -1e30f;
    s[threadIdx.x] = m;
    __syncthreads();
    for (int st = 128; st > 0; st >>= 1) {
        if (threadIdx.x < st) s[threadIdx.x] = fmaxf(s[threadIdx.x], s[threadIdx.x + st]);
        __syncthreads();
    }
    if (threadIdx.x == 0) out[0] = s[0];
}

__global__ void scale_xs_kernel(float* __restrict__ xs, const float* __restrict__ alpha,
                                const float* __restrict__ mval)
{
    int idx = blockIdx.x * 256 + threadIdx.x;
    int p = idx % PIX;
    int q = idx / PIX;
    int d = q % ND;
    int bb = (q / ND) / TIN;
    xs[idx] *= __expf(alpha[(bb * ND + d) * PIX + p] - mval[0]);
}

// ---------------------------------------------------------------------------
__global__ void tcnn_kernel(const float* __restrict__ yprev, const float* __restrict__ hl,
                            const float* __restrict__ tw, const float* __restrict__ tb,
                            float* __restrict__ ynext, float* __restrict__ hcarry,
                            float* __restrict__ outp)
{
    int p = blockIdx.x * 256 + threadIdx.x;
    int bb = blockIdx.y;
    float acc = tb[0];
#pragma unroll
    for (int cc = 0; cc < TIN; ++cc)
        acc = fmaf(tw[cc], yprev[(bb * TIN + cc) * PIX + p], acc);
    float hv = hl[bb * PIX + p];
    acc = fmaf(tw[TIN], hv, acc);
    float o = fmaxf(acc, 0.0f);
    outp[bb * TOUT * PIX + p] = o;
#pragma unroll
    for (int cc = 0; cc < TIN - 1; ++cc)
        ynext[(bb * TIN + cc) * PIX + p] = yprev[(bb * TIN + cc + 1) * PIX + p];
    ynext[(bb * TIN + 9) * PIX + p] = hv;
    hcarry[bb * PIX + p] = o;
}

__global__ void slice_y_kernel(const float* __restrict__ x, float* __restrict__ yp)
{
    int idx = blockIdx.x * 256 + threadIdx.x;
    int p = idx % PIX;
    int q = idx / PIX;
    yp[idx] = x[(size_t)(q * ND + 0) * PIX + p];
}

// ---------------------------------------------------------------------------
extern "C" void kernel_launch(void* const* d_in, const int* in_sizes, int n_in,
                              void* d_out, int out_size, void* d_ws, size_t ws_size,
                              hipStream_t stream)
{
    const float* x       = (const float*)d_in[0];
    const float* enc_w0  = (const float*)d_in[1];
    const float* enc_b0  = (const float*)d_in[2];
    const float* enc_w1  = (const float*)d_in[3];
    const float* enc_b1  = (const float*)d_in[4];
    const float* enc_w2  = (const float*)d_in[5];
    const float* enc_b2  = (const float*)d_in[6];
    const float* dec_w0  = (const float*)d_in[7];
    const float* dec_b0  = (const float*)d_in[8];
    const float* dec_w1  = (const float*)d_in[9];
    const float* dec_b1  = (const float*)d_in[10];
    const float* dec_w2  = (const float*)d_in[11];
    const float* dec_b2  = (const float*)d_in[12];
    const float* attn_wi = (const float*)d_in[13];
    const float* attn_bi = (const float*)d_in[14];
    const float* attn_wh = (const float*)d_in[15];
    const float* attn_bh = (const float*)d_in[16];
    const float* attn_wv = (const float*)d_in[17];
    const float* attn_bv = (const float*)d_in[18];
    const float* tcnn_w  = (const float*)d_in[19];
    const float* tcnn_b  = (const float*)d_in[20];
    float* out = (float*)d_out;

    char* cur = (char*)d_ws;
    auto alloc = [&](size_t bytes) { char* p = cur; cur += (bytes + 255) & ~(size_t)255; return p; };
    float* xs   = (float*)alloc((size_t)NB * TIN * ND * PIX * 4);
    float* h0a  = (float*)alloc(NB * PIX * 4);
    float* h0b  = (float*)alloc(NB * PIX * 4);
    float* c0   = (float*)alloc(NB * PIX * 4);
    float* hl   = (float*)alloc(NB * PIX * 4);
    float* c1   = (float*)alloc((size_t)NB * HID * PIX * 4);
    float* c2   = (float*)alloc((size_t)NB * HID * PIX * 4);
    float* alp  = (float*)alloc((size_t)NB * ND * PIX * 4);
    float* ypa  = (float*)alloc((size_t)NB * TIN * PIX * 4);
    float* ypb  = (float*)alloc((size_t)NB * TIN * PIX * 4);
    float* partial = (float*)alloc(1024);
    float* mval = (float*)alloc(256);
    const size_t IN1_B = (size_t)NB * 12 * PIX * 8 * 2;   // 96ch packed
    const size_t IN2_B = (size_t)NB * 16 * PIX * 8 * 2;   // 128ch packed
    unsigned short* In1a = (unsigned short*)alloc(IN1_B);
    unsigned short* In1b = (unsigned short*)alloc(IN1_B);
    unsigned short* In2a = (unsigned short*)alloc(IN2_B);
    unsigned short* In2b = (unsigned short*)alloc(IN2_B);
    unsigned short* wpe1 = (unsigned short*)alloc((size_t)9 * 3 * 256 * 32 * 2);
    unsigned short* wpe2 = (unsigned short*)alloc((size_t)9 * 4 * 256 * 32 * 2);
    unsigned short* wpd0 = (unsigned short*)alloc((size_t)9 * 2 * 256 * 32 * 2);
    unsigned short* wpd1 = (unsigned short*)alloc((size_t)9 * 4 * 256 * 32 * 2);

    hipMemcpyAsync(xs, x, (size_t)NB * TIN * ND * PIX * 4, hipMemcpyDeviceToDevice, stream);
    hipMemsetAsync(h0a, 0, NB * PIX * 4, stream);
    hipMemsetAsync(c0,  0, NB * PIX * 4, stream);
    hipMemsetAsync(c1,  0, (size_t)NB * HID * PIX * 4, stream);
    hipMemsetAsync(c2,  0, (size_t)NB * HID * PIX * 4, stream);
    hipMemsetAsync(In1a, 0, IN1_B, stream);
    hipMemsetAsync(In1b, 0, IN1_B, stream);
    hipMemsetAsync(In2a, 0, IN2_B, stream);
    hipMemsetAsync(In2b, 0, IN2_B, stream);
    slice_y_kernel<<<dim3(1440), 256, 0, stream>>>(x, ypa);

    wpack_kernel<<<dim3(864),  256, 0, stream>>>(enc_w1, wpe1, 65, 3, 0, 65);
    wpack_kernel<<<dim3(1152), 256, 0, stream>>>(enc_w2, wpe2, 128, 4, 0, 128);
    wpack_kernel<<<dim3(576),  256, 0, stream>>>(dec_w0, wpd0, 65, 2, 1, 64);   // skip zero x-ch
    wpack_kernel<<<dim3(1152), 256, 0, stream>>>(dec_w1, wpd1, 128, 4, 0, 128);

    dim3 big_grid(2, 96, NB), big_block(64, 4);
    float *h0 = h0a, *h0n = h0b;
    unsigned short *i1c = In1a, *i1n = In1b, *i2c = In2a, *i2n = In2b;

    // ---------------- encoder ----------------
    for (int t = 0; t < TIN; ++t) {
        attn_fused<<<dim3(96, ND, NB), 256, 0, stream>>>(xs, h0, c0, attn_wi, attn_bi,
                                                         attn_wh, attn_bh, attn_wv, attn_bv, alp);
        redmax1_kernel<<<dim3(144), 256, 0, stream>>>(alp, NB * ND * PIX, partial);
        redmax2_kernel<<<dim3(1), 256, 0, stream>>>(partial, 144, mval);
        scale_xs_kernel<<<dim3(7200), 256, 0, stream>>>(xs, alp, mval);

        small_cell5<<<dim3(36, NB), 256, 0, stream>>>(xs + (size_t)t * ND * PIX, h0, c0,
                                                      enc_w0, enc_b0, h0n, c0, i1c, 12);
        { float* tmp = h0; h0 = h0n; h0n = tmp; }

        // enc1: reads i1c (ch0=h0[t], ch1-64=h1[t-1]); writes h1[t]
        unsigned short* e1d1 = (t < TIN - 1) ? i1n : In2a;          // final -> dec1 h slot
        int e1o = (t < TIN - 1) ? 1 : 64;
        int e1n = (t < TIN - 1) ? 12 : 16;
        cell64_mfma<3><<<big_grid, big_block, 0, stream>>>(i1c, wpe1, enc_b1, c1, c1,
                                                           e1d1, e1o, e1n, i2c, 0, 16);
        // enc2: reads i2c (ch0-63=h1[t], ch64-127=h2[t-1]); writes h2[t]
        unsigned short* e2d1 = (t < TIN - 1) ? i2n : In1a;          // final -> dec0 x slot
        int e2o = (t < TIN - 1) ? 64 : 0;
        int e2n = (t < TIN - 1) ? 16 : 8;
        cell64_mfma<4><<<big_grid, big_block, 0, stream>>>(i2c, wpe2, enc_b2, c2, c2,
                                                           e2d1, e2o, e2n, nullptr, 0, 0);
        { unsigned short* tmp = i1c; i1c = i1n; i1n = tmp; }
        { unsigned short* tmp = i2c; i2c = i2n; i2n = tmp; }
    }

    // ---------------- decoder ----------------
    // aliases: d0 buffers over In1 region (8cg layout), d1 buffers over In2 (16cg)
    unsigned short *d0c = In1a, *d0n = In1b, *d1c = In2a, *d1n = In2b;
    float *yp = ypa, *ypn = ypb, *hc = h0, *hcn = h0n;
    for (int t = 0; t < TOUT; ++t) {
        cell64_mfma<2><<<big_grid, big_block, 0, stream>>>(d0c, wpd0, dec_b0, c2, c2,
                                                           d0n, 0, 8, d1c, 0, 16);
        cell64_mfma<4><<<big_grid, big_block, 0, stream>>>(d1c, wpd1, dec_b1, c1, c1,
                                                           d1n, 64, 16, nullptr, 0, 0);
        small_cell64<<<dim3(36, NB), 256, 0, stream>>>(d1n, 16, 64, hc, c0,
                                                       dec_w2, dec_b2, hl, c0);
        tcnn_kernel<<<dim3(36, NB), 256, 0, stream>>>(yp, hl, tcnn_w, tcnn_b, ypn, hcn,
                                                      out + (size_t)t * PIX);
        { unsigned short* tmp = d0c; d0c = d0n; d0n = tmp; }
        { unsigned short* tmp = d1c; d1c = d1n; d1n = tmp; }
        { float* tmp = yp; yp = ypn; ypn = tmp; }
        { float* tmp = hc; hc = hcn; hcn = tmp; }
    }
}

// Round 3
// 2165.940 us; speedup vs baseline: 6.5087x; 4.7017x over previous
//
#include <hip/hip_runtime.h>

// WeatherModel: ConvLSTM encoder-decoder with attention.
// Big ConvLSTM cells + attention e-conv via bf16 MFMA implicit GEMM.
// B=4, T_IN=10, T_OUT=5, D=5, M=N=96, H1=64, ATTN=32, SEL=0.

#define PIX  9216
#define NB   4
#define TIN  10
#define TOUT 5
#define ND   5
#define HID  64

typedef __attribute__((ext_vector_type(8))) short bf16x8;
typedef __attribute__((ext_vector_type(4))) float f32x4;

__device__ __forceinline__ float sigmf_(float x) { return 1.0f / (1.0f + __expf(-x)); }
__device__ __forceinline__ float tanhf_(float x) { return 1.0f - 2.0f / (__expf(2.0f * x) + 1.0f); }
__device__ __forceinline__ unsigned short f2bf(float f) {
    unsigned u = __float_as_uint(f);
    unsigned r = u + 0x7FFFu + ((u >> 16) & 1u);
    return (unsigned short)(r >> 16);
}
__device__ __forceinline__ float bf2f(unsigned short u) {
    return __uint_as_float(((unsigned)u) << 16);
}

// ---------------------------------------------------------------------------
// Big ConvLSTM cell, implicit-GEMM MFMA (validated round 1).
// ---------------------------------------------------------------------------
template <int NCH>
__global__ void __launch_bounds__(256, 3)
cell64_mfma(const unsigned short* __restrict__ inP,
            const unsigned short* __restrict__ wP,
            const float* __restrict__ bias,
            const float* cprev, float* cout,
            unsigned short* __restrict__ d1, int d1_coff, int d1_ncg,
            unsigned short* __restrict__ d2, int d2_coff, int d2_ncg)
{
    __shared__ __align__(16) char smem[49152];
    const int lane = threadIdx.x;
    const int wv   = threadIdx.y;
    const int tid  = wv * 64 + lane;
    const int xh = blockIdx.x, y = blockIdx.y, b = blockIdx.z;
    const int x0 = xh * 48;
    const int l15 = lane & 15, l4 = lane >> 4;
    const int NCG = NCH * 4;

    f32x4 acc[4][3] = {};

    for (int cc = 0; cc < NCH; ++cc) {
        for (int g = tid; g < 600; g += 256) {
            int pr = g >> 2;
            int cg = g & 3;
            int r = pr / 50;
            int p = pr - r * 50;
            int gy = y - 1 + r, gx = x0 - 1 + p;
            uint4 v = make_uint4(0u, 0u, 0u, 0u);
            if ((unsigned)gy < 96u && (unsigned)gx < 96u)
                v = *(const uint4*)(inP + (((size_t)(b * NCG + cc * 4 + cg) * 9216
                                            + gy * 96 + gx) << 3));
            int slot = cg ^ ((p >> 1) & 3);
            *(uint4*)(smem + pr * 64 + slot * 16) = v;
        }
        __syncthreads();

#pragma unroll
        for (int ky = 0; ky < 3; ++ky) {
#pragma unroll
            for (int kx = 0; kx < 3; ++kx) {
                const int tap = ky * 3 + kx;
                const bf16x8* ap = (const bf16x8*)(wP
                    + ((size_t)(tap * NCH + cc) * 256 + wv * 64 + l15) * 32 + l4 * 8);
                bf16x8 af[4];
                af[0] = ap[0]; af[1] = ap[64]; af[2] = ap[128]; af[3] = ap[192];
                bf16x8 bk[3];
#pragma unroll
                for (int k = 0; k < 3; ++k) {
                    int p = k * 16 + kx + l15;
                    int slot = l4 ^ ((p >> 1) & 3);
                    bk[k] = *(const bf16x8*)(smem + (ky * 50 + p) * 64 + slot * 16);
                }
#pragma unroll
                for (int f = 0; f < 4; ++f)
#pragma unroll
                    for (int k = 0; k < 3; ++k)
                        acc[f][k] = __builtin_amdgcn_mfma_f32_16x16x32_bf16(
                            af[f], bk[k], acc[f][k], 0, 0, 0);
            }
        }
        __syncthreads();
    }

    float* zb = (float*)smem;
#pragma unroll
    for (int f = 0; f < 4; ++f)
#pragma unroll
        for (int k = 0; k < 3; ++k)
#pragma unroll
            for (int r = 0; r < 4; ++r) {
                int hc = f * 16 + l4 * 4 + r;
                int px = k * 16 + l15;
                zb[(wv * 64 + hc) * 48 + px] = acc[f][k][r];
            }
    __syncthreads();

    for (int i = 0; i < 12; ++i) {
        int e = i * 256 + tid;
        int hc = e / 48, px = e - hc * 48;
        float zi = zb[(0 * 64 + hc) * 48 + px];
        float zf = zb[(1 * 64 + hc) * 48 + px];
        float zo = zb[(2 * 64 + hc) * 48 + px];
        float zg = zb[(3 * 64 + hc) * 48 + px];
        float ii = sigmf_(zi + bias[hc]);
        float ff = sigmf_(zf + bias[64 + hc]);
        float oo = sigmf_(zo + bias[128 + hc]);
        float gg = tanhf_(zg + bias[192 + hc]);
        int gpix = y * 96 + x0 + px;
        int cidx = (b * HID + hc) * 9216 + gpix;
        float cn = ff * cprev[cidx] + ii * gg;
        cout[cidx] = cn;
        unsigned short hb = f2bf(oo * tanhf_(cn));
        int ch1 = d1_coff + hc;
        d1[((size_t)(b * d1_ncg + (ch1 >> 3)) * 9216 + gpix) * 8 + (ch1 & 7)] = hb;
        if (d2) {
            int ch2 = d2_coff + hc;
            d2[((size_t)(b * d2_ncg + (ch2 >> 3)) * 9216 + gpix) * 8 + (ch2 & 7)] = hb;
        }
    }
}

__global__ void wpack_kernel(const float* __restrict__ w, unsigned short* __restrict__ wp,
                             int WCIN, int NCH, int coff, int climit)
{
    int idx = blockIdx.x * 256 + threadIdx.x;
    int total = 9 * NCH * 256 * 32;
    if (idx >= total) return;
    int k = idx & 31;
    int oc = (idx >> 5) & 255;
    int rest = idx >> 13;
    int cc = rest % NCH, tap = rest / NCH;
    int c = cc * 32 + k;
    float v = 0.0f;
    if (c < climit) v = w[(oc * WCIN + (c + coff)) * 9 + tap];
    wp[idx] = f2bf(v);
}

// ---------------------------------------------------------------------------
// Small ConvLSTM cells (hidden=1).
// ---------------------------------------------------------------------------
__global__ void small_cell5(const float* __restrict__ xs_t,
                            const float* __restrict__ hprev, const float* cprev,
                            const float* __restrict__ w, const float* __restrict__ bias,
                            float* __restrict__ hout, float* cout,
                            unsigned short* __restrict__ pk, int ncg)
{
    int p = blockIdx.x * 256 + threadIdx.x;
    int bb = blockIdx.y;
    int y = p / 96, x = p - y * 96;
    float acc[4] = { bias[0], bias[1], bias[2], bias[3] };
    for (int cin = 0; cin < 6; ++cin) {
        const float* src = (cin < 5) ? (xs_t + (bb * TIN * ND + cin) * PIX)
                                     : (hprev + bb * PIX);
#pragma unroll
        for (int ky = 0; ky < 3; ++ky) {
            int gy = y + ky - 1;
            if ((unsigned)gy >= 96u) continue;
#pragma unroll
            for (int kx = 0; kx < 3; ++kx) {
                int gx = x + kx - 1;
                if ((unsigned)gx >= 96u) continue;
                float v = src[gy * 96 + gx];
#pragma unroll
                for (int g = 0; g < 4; ++g)
                    acc[g] = fmaf(w[(g * 6 + cin) * 9 + ky * 3 + kx], v, acc[g]);
            }
        }
    }
    int idx = bb * PIX + p;
    float cn = sigmf_(acc[1]) * cprev[idx] + sigmf_(acc[0]) * tanhf_(acc[3]);
    cout[idx] = cn;
    float h = sigmf_(acc[2]) * tanhf_(cn);
    hout[idx] = h;
    pk[((size_t)(bb * ncg) * 9216 + p) * 8] = f2bf(h);
}

__global__ void small_cell64(const unsigned short* __restrict__ xin, int ncg, int cbase,
                             const float* __restrict__ hprev, const float* cprev,
                             const float* __restrict__ w, const float* __restrict__ bias,
                             float* __restrict__ hout, float* cout)
{
    int p = blockIdx.x * 256 + threadIdx.x;
    int bb = blockIdx.y;
    int y = p / 96, x = p - y * 96;
    float acc[4] = { bias[0], bias[1], bias[2], bias[3] };
    for (int cin = 0; cin < 65; ++cin) {
#pragma unroll
        for (int ky = 0; ky < 3; ++ky) {
            int gy = y + ky - 1;
            if ((unsigned)gy >= 96u) continue;
#pragma unroll
            for (int kx = 0; kx < 3; ++kx) {
                int gx = x + kx - 1;
                if ((unsigned)gx >= 96u) continue;
                float v;
                if (cin < 64) {
                    int ch = cbase + cin;
                    v = bf2f(xin[((size_t)(bb * ncg + (ch >> 3)) * 9216
                                  + gy * 96 + gx) * 8 + (ch & 7)]);
                } else {
                    v = hprev[bb * PIX + gy * 96 + gx];
                }
#pragma unroll
                for (int g = 0; g < 4; ++g)
                    acc[g] = fmaf(w[(g * 65 + cin) * 9 + ky * 3 + kx], v, acc[g]);
            }
        }
    }
    int idx = bb * PIX + p;
    float cn = sigmf_(acc[1]) * cprev[idx] + sigmf_(acc[0]) * tanhf_(acc[3]);
    cout[idx] = cn;
    hout[idx] = sigmf_(acc[2]) * tanhf_(cn);
}

// ---------------------------------------------------------------------------
// Attention, MFMA edition.
// xsp: packed xs bf16 [b][d][pix][16]  (ch = t 0..9, 10..15 zero)
// wiP: packed wi bf16 [j 0..4][32 oc][32 K]  K-local: (tappos<<4)|ch, tap=2j+tappos
// heP: hidE fp32 [b][pix][32]  (includes bi+bh)
// eP : e bf16 [b*5+k][pix][32]
// ---------------------------------------------------------------------------
__global__ void pack_wi_kernel(const float* __restrict__ wi, unsigned short* __restrict__ wiP)
{
    int idx = blockIdx.x * 256 + threadIdx.x;      // 5*32*32 = 5120
    if (idx >= 5120) return;
    int kl = idx & 31, oc = (idx >> 5) & 31, j = idx >> 10;
    int tappos = kl >> 4, ch = kl & 15;
    int tap = 2 * j + tappos;
    float v = 0.0f;
    if (tap < 9 && ch < 10) v = wi[(oc * TIN + ch) * 9 + tap];
    wiP[idx] = f2bf(v);
}

__global__ void hidE_kernel(const float* __restrict__ h0, const float* __restrict__ c0,
                            const float* __restrict__ wh, const float* __restrict__ bh,
                            const float* __restrict__ bi, float* __restrict__ heP)
{
    int idx = blockIdx.x * 256 + threadIdx.x;      // 9216*4
    int bb = blockIdx.y;
    int cg = idx & 3, p = idx >> 2;
    int y = p / 96, x = p - y * 96;
    float acc[8];
#pragma unroll
    for (int j = 0; j < 8; ++j) acc[j] = bi[cg * 8 + j] + bh[cg * 8 + j];
#pragma unroll
    for (int cin = 0; cin < 2; ++cin) {
        const float* src = (cin == 0 ? h0 : c0) + bb * PIX;
#pragma unroll
        for (int ky = 0; ky < 3; ++ky) {
            int gy = y + ky - 1;
            if ((unsigned)gy >= 96u) continue;
#pragma unroll
            for (int kx = 0; kx < 3; ++kx) {
                int gx = x + kx - 1;
                if ((unsigned)gx >= 96u) continue;
                float v = src[gy * 96 + gx];
#pragma unroll
                for (int j = 0; j < 8; ++j)
                    acc[j] = fmaf(wh[((cg * 8 + j) * 2 + cin) * 9 + ky * 3 + kx], v, acc[j]);
            }
        }
    }
    float* dst = heP + ((size_t)(bb * PIX) + p) * 32 + cg * 8;
    *(float4*)dst = make_float4(acc[0], acc[1], acc[2], acc[3]);
    *(float4*)(dst + 4) = make_float4(acc[4], acc[5], acc[6], acc[7]);
}

__global__ void __launch_bounds__(256)
attn_e_mfma(const unsigned short* __restrict__ xsp, const unsigned short* __restrict__ wiP,
            const float* __restrict__ heP, unsigned short* __restrict__ eP)
{
    const int lane = threadIdx.x, wvid = threadIdx.y;
    const int tile = blockIdx.x, k = blockIdx.y, bb = blockIdx.z;
    const int l15 = lane & 15, l4 = lane >> 4;

    bf16x8 af[5][2];
#pragma unroll
    for (int j = 0; j < 5; ++j)
#pragma unroll
        for (int m = 0; m < 2; ++m)
            af[j][m] = *(const bf16x8*)(wiP + ((size_t)(j * 32 + m * 16 + l15)) * 32 + l4 * 8);

    const unsigned short* xb = xsp + (size_t)(bb * ND + k) * PIX * 16;
    const int p0 = tile * 256 + wvid * 64;
    const int tap = 2 * 0 + (l4 >> 1);             // recomputed per j below
    (void)tap;

    f32x4 acc[4][2] = {};
#pragma unroll
    for (int nf = 0; nf < 4; ++nf) {
        int p = p0 + nf * 16 + l15;
        int y = p / 96, x = p - y * 96;
#pragma unroll
        for (int j = 0; j < 5; ++j) {
            int tp = 2 * j + (l4 >> 1);
            bf16x8 bk = { 0, 0, 0, 0, 0, 0, 0, 0 };
            if (tp < 9) {
                int gy = y + tp / 3 - 1, gx = x + tp % 3 - 1;
                if ((unsigned)gy < 96u && (unsigned)gx < 96u)
                    bk = *(const bf16x8*)(xb + ((size_t)(gy * 96 + gx)) * 16 + (l4 & 1) * 8);
            }
            acc[nf][0] = __builtin_amdgcn_mfma_f32_16x16x32_bf16(af[j][0], bk, acc[nf][0], 0, 0, 0);
            acc[nf][1] = __builtin_amdgcn_mfma_f32_16x16x32_bf16(af[j][1], bk, acc[nf][1], 0, 0, 0);
        }
    }

#pragma unroll
    for (int nf = 0; nf < 4; ++nf) {
        int p = p0 + nf * 16 + l15;
#pragma unroll
        for (int m = 0; m < 2; ++m) {
            const float4 he = *(const float4*)(heP + ((size_t)(bb * PIX) + p) * 32 + m * 16 + l4 * 4);
            ushort4 o;
            o.x = f2bf(tanhf_(acc[nf][m][0] + he.x));
            o.y = f2bf(tanhf_(acc[nf][m][1] + he.y));
            o.z = f2bf(tanhf_(acc[nf][m][2] + he.z));
            o.w = f2bf(tanhf_(acc[nf][m][3] + he.w));
            *(ushort4*)(eP + ((size_t)(bb * ND + k) * PIX + p) * 32 + m * 16 + l4 * 4) = o;
        }
    }
}

__global__ void __launch_bounds__(256)
attn_alpha(const unsigned short* __restrict__ eP, const float* __restrict__ wvv,
           const float* __restrict__ bv, float* __restrict__ alpha,
           float* __restrict__ partial)
{
    int p = blockIdx.x * 256 + threadIdx.x;
    int k = blockIdx.y, bb = blockIdx.z;
    int y = p / 96, x = p - y * 96;
    const unsigned short* eb = eP + (size_t)(bb * ND + k) * PIX * 32;
    float acc = bv[0];
#pragma unroll
    for (int ky = 0; ky < 3; ++ky) {
        int gy = y + ky - 1;
        if ((unsigned)gy >= 96u) continue;
#pragma unroll
        for (int kx = 0; kx < 3; ++kx) {
            int gx = x + kx - 1;
            if ((unsigned)gx >= 96u) continue;
            int tap = ky * 3 + kx;
            const unsigned short* ee = eb + ((size_t)(gy * 96 + gx)) * 32;
#pragma unroll
            for (int cg = 0; cg < 4; ++cg) {
                bf16x8 ev = *(const bf16x8*)(ee + cg * 8);
#pragma unroll
                for (int jj = 0; jj < 8; ++jj)
                    acc = fmaf(wvv[(cg * 8 + jj) * 9 + tap], bf2f((unsigned short)ev[jj]), acc);
            }
        }
    }
    alpha[(size_t)(bb * ND + k) * PIX + p] = acc;

    __shared__ float s[256];
    s[threadIdx.x] = acc;
    __syncthreads();
    for (int st = 128; st > 0; st >>= 1) {
        if (threadIdx.x < st) s[threadIdx.x] = fmaxf(s[threadIdx.x], s[threadIdx.x + st]);
        __syncthreads();
    }
    if (threadIdx.x == 0) partial[(bb * ND + k) * 36 + blockIdx.x] = s[0];
}

__global__ void redmax2_kernel(const float* __restrict__ partial, int n, float* __restrict__ out)
{
    __shared__ float s[256];
    float m = -1e30f;
    for (int i = threadIdx.x; i < n; i += 256) m = fmaxf(m, partial[i]);
    s[threadIdx.x] = m;
    __syncthreads();
    for (int st = 128; st > 0; st >>= 1) {
        if (threadIdx.x < st) s[threadIdx.x] = fmaxf(s[threadIdx.x], s[threadIdx.x + st]);
        __syncthreads();
    }
    if (threadIdx.x == 0) out[0] = s[0];
}

// per (b,d,p): scale all 10 t of xs, repack xsp row
__global__ void scale_pack_kernel(float* __restrict__ xs, unsigned short* __restrict__ xsp,
                                  const float* __restrict__ alpha, const float* __restrict__ mval)
{
    int idx = blockIdx.x * 256 + threadIdx.x;      // b*5*9216
    int p = idx % PIX;
    int q = idx / PIX;
    int d = q % ND, bb = q / ND;
    float w = __expf(alpha[idx] - mval[0]);
    unsigned short tmp[16];
#pragma unroll
    for (int t = 0; t < TIN; ++t) {
        size_t xi = ((size_t)(bb * TIN + t) * ND + d) * PIX + p;
        float v = xs[xi] * w;
        xs[xi] = v;
        tmp[t] = f2bf(v);
    }
#pragma unroll
    for (int t = TIN; t < 16; ++t) tmp[t] = 0;
    uint4* dst = (uint4*)(xsp + (size_t)idx * 16);
    dst[0] = *(uint4*)&tmp[0];
    dst[1] = *(uint4*)&tmp[8];
}

__global__ void pack_xsp_kernel(const float* __restrict__ x, unsigned short* __restrict__ xsp)
{
    int idx = blockIdx.x * 256 + threadIdx.x;      // b*5*9216
    int p = idx % PIX;
    int q = idx / PIX;
    int d = q % ND, bb = q / ND;
    unsigned short tmp[16];
#pragma unroll
    for (int t = 0; t < TIN; ++t)
        tmp[t] = f2bf(x[((size_t)(bb * TIN + t) * ND + d) * PIX + p]);
#pragma unroll
    for (int t = TIN; t < 16; ++t) tmp[t] = 0;
    uint4* dst = (uint4*)(xsp + (size_t)idx * 16);
    dst[0] = *(uint4*)&tmp[0];
    dst[1] = *(uint4*)&tmp[8];
}

// ---------------------------------------------------------------------------
__global__ void tcnn_kernel(const float* __restrict__ yprev, const float* __restrict__ hl,
                            const float* __restrict__ tw, const float* __restrict__ tb,
                            float* __restrict__ ynext, float* __restrict__ hcarry,
                            float* __restrict__ outp)
{
    int p = blockIdx.x * 256 + threadIdx.x;
    int bb = blockIdx.y;
    float acc = tb[0];
#pragma unroll
    for (int cc = 0; cc < TIN; ++cc)
        acc = fmaf(tw[cc], yprev[(bb * TIN + cc) * PIX + p], acc);
    float hv = hl[bb * PIX + p];
    acc = fmaf(tw[TIN], hv, acc);
    float o = fmaxf(acc, 0.0f);
    outp[bb * TOUT * PIX + p] = o;
#pragma unroll
    for (int cc = 0; cc < TIN - 1; ++cc)
        ynext[(bb * TIN + cc) * PIX + p] = yprev[(bb * TIN + cc + 1) * PIX + p];
    ynext[(bb * TIN + 9) * PIX + p] = hv;
    hcarry[bb * PIX + p] = o;
}

__global__ void slice_y_kernel(const float* __restrict__ x, float* __restrict__ yp)
{
    int idx = blockIdx.x * 256 + threadIdx.x;
    int p = idx % PIX;
    int q = idx / PIX;
    yp[idx] = x[(size_t)(q * ND + 0) * PIX + p];
}

// ---------------------------------------------------------------------------
extern "C" void kernel_launch(void* const* d_in, const int* in_sizes, int n_in,
                              void* d_out, int out_size, void* d_ws, size_t ws_size,
                              hipStream_t stream)
{
    const float* x       = (const float*)d_in[0];
    const float* enc_w0  = (const float*)d_in[1];
    const float* enc_b0  = (const float*)d_in[2];
    const float* enc_w1  = (const float*)d_in[3];
    const float* enc_b1  = (const float*)d_in[4];
    const float* enc_w2  = (const float*)d_in[5];
    const float* enc_b2  = (const float*)d_in[6];
    const float* dec_w0  = (const float*)d_in[7];
    const float* dec_b0  = (const float*)d_in[8];
    const float* dec_w1  = (const float*)d_in[9];
    const float* dec_b1  = (const float*)d_in[10];
    const float* dec_w2  = (const float*)d_in[11];
    const float* dec_b2  = (const float*)d_in[12];
    const float* attn_wi = (const float*)d_in[13];
    const float* attn_bi = (const float*)d_in[14];
    const float* attn_wh = (const float*)d_in[15];
    const float* attn_bh = (const float*)d_in[16];
    const float* attn_wv = (const float*)d_in[17];
    const float* attn_bv = (const float*)d_in[18];
    const float* tcnn_w  = (const float*)d_in[19];
    const float* tcnn_b  = (const float*)d_in[20];
    float* out = (float*)d_out;

    char* cur = (char*)d_ws;
    auto alloc = [&](size_t bytes) { char* p = cur; cur += (bytes + 255) & ~(size_t)255; return p; };
    float* xs   = (float*)alloc((size_t)NB * TIN * ND * PIX * 4);
    float* h0a  = (float*)alloc(NB * PIX * 4);
    float* h0b  = (float*)alloc(NB * PIX * 4);
    float* c0   = (float*)alloc(NB * PIX * 4);
    float* hl   = (float*)alloc(NB * PIX * 4);
    float* c1   = (float*)alloc((size_t)NB * HID * PIX * 4);
    float* c2   = (float*)alloc((size_t)NB * HID * PIX * 4);
    float* alp  = (float*)alloc((size_t)NB * ND * PIX * 4);
    float* ypa  = (float*)alloc((size_t)NB * TIN * PIX * 4);
    float* ypb  = (float*)alloc((size_t)NB * TIN * PIX * 4);
    float* partial = (float*)alloc(4096);
    float* mval = (float*)alloc(256);
    const size_t IN1_B = (size_t)NB * 12 * PIX * 8 * 2;
    const size_t IN2_B = (size_t)NB * 16 * PIX * 8 * 2;
    unsigned short* In1a = (unsigned short*)alloc(IN1_B);
    unsigned short* In1b = (unsigned short*)alloc(IN1_B);
    unsigned short* In2a = (unsigned short*)alloc(IN2_B);
    unsigned short* In2b = (unsigned short*)alloc(IN2_B);
    unsigned short* wpe1 = (unsigned short*)alloc((size_t)9 * 3 * 256 * 32 * 2);
    unsigned short* wpe2 = (unsigned short*)alloc((size_t)9 * 4 * 256 * 32 * 2);
    unsigned short* wpd0 = (unsigned short*)alloc((size_t)9 * 2 * 256 * 32 * 2);
    unsigned short* wpd1 = (unsigned short*)alloc((size_t)9 * 4 * 256 * 32 * 2);
    unsigned short* xsp  = (unsigned short*)alloc((size_t)NB * ND * PIX * 16 * 2);
    unsigned short* wiP  = (unsigned short*)alloc(5120 * 2);
    float* heP = (float*)alloc((size_t)NB * PIX * 32 * 4);
    unsigned short* eP = (unsigned short*)alloc((size_t)NB * ND * PIX * 32 * 2);

    hipMemcpyAsync(xs, x, (size_t)NB * TIN * ND * PIX * 4, hipMemcpyDeviceToDevice, stream);
    hipMemsetAsync(h0a, 0, NB * PIX * 4, stream);
    hipMemsetAsync(c0,  0, NB * PIX * 4, stream);
    hipMemsetAsync(c1,  0, (size_t)NB * HID * PIX * 4, stream);
    hipMemsetAsync(c2,  0, (size_t)NB * HID * PIX * 4, stream);
    hipMemsetAsync(In1a, 0, IN1_B, stream);
    hipMemsetAsync(In1b, 0, IN1_B, stream);
    hipMemsetAsync(In2a, 0, IN2_B, stream);
    hipMemsetAsync(In2b, 0, IN2_B, stream);
    slice_y_kernel<<<dim3(1440), 256, 0, stream>>>(x, ypa);

    wpack_kernel<<<dim3(864),  256, 0, stream>>>(enc_w1, wpe1, 65, 3, 0, 65);
    wpack_kernel<<<dim3(1152), 256, 0, stream>>>(enc_w2, wpe2, 128, 4, 0, 128);
    wpack_kernel<<<dim3(576),  256, 0, stream>>>(dec_w0, wpd0, 65, 2, 1, 64);
    wpack_kernel<<<dim3(1152), 256, 0, stream>>>(dec_w1, wpd1, 128, 4, 0, 128);
    pack_wi_kernel<<<dim3(20), 256, 0, stream>>>(attn_wi, wiP);
    pack_xsp_kernel<<<dim3(720), 256, 0, stream>>>(x, xsp);

    dim3 big_grid(2, 96, NB), big_block(64, 4);
    dim3 attn_block(64, 4);
    float *h0 = h0a, *h0n = h0b;
    unsigned short *i1c = In1a, *i1n = In1b, *i2c = In2a, *i2n = In2b;

    // ---------------- encoder ----------------
    for (int t = 0; t < TIN; ++t) {
        hidE_kernel<<<dim3(144, NB), 256, 0, stream>>>(h0, c0, attn_wh, attn_bh, attn_bi, heP);
        attn_e_mfma<<<dim3(36, ND, NB), attn_block, 0, stream>>>(xsp, wiP, heP, eP);
        attn_alpha<<<dim3(36, ND, NB), 256, 0, stream>>>(eP, attn_wv, attn_bv, alp, partial);
        redmax2_kernel<<<dim3(1), 256, 0, stream>>>(partial, 720, mval);
        scale_pack_kernel<<<dim3(720), 256, 0, stream>>>(xs, xsp, alp, mval);

        small_cell5<<<dim3(36, NB), 256, 0, stream>>>(xs + (size_t)t * ND * PIX, h0, c0,
                                                      enc_w0, enc_b0, h0n, c0, i1c, 12);
        { float* tmp = h0; h0 = h0n; h0n = tmp; }

        unsigned short* e1d1 = (t < TIN - 1) ? i1n : In2a;
        int e1o = (t < TIN - 1) ? 1 : 64;
        int e1n = (t < TIN - 1) ? 12 : 16;
        cell64_mfma<3><<<big_grid, big_block, 0, stream>>>(i1c, wpe1, enc_b1, c1, c1,
                                                           e1d1, e1o, e1n, i2c, 0, 16);
        unsigned short* e2d1 = (t < TIN - 1) ? i2n : In1a;
        int e2o = (t < TIN - 1) ? 64 : 0;
        int e2n = (t < TIN - 1) ? 16 : 8;
        cell64_mfma<4><<<big_grid, big_block, 0, stream>>>(i2c, wpe2, enc_b2, c2, c2,
                                                           e2d1, e2o, e2n, nullptr, 0, 0);
        { unsigned short* tmp = i1c; i1c = i1n; i1n = tmp; }
        { unsigned short* tmp = i2c; i2c = i2n; i2n = tmp; }
    }

    // ---------------- decoder ----------------
    unsigned short *d0c = In1a, *d0n = In1b, *d1c = In2a, *d1n = In2b;
    float *yp = ypa, *ypn = ypb, *hc = h0, *hcn = h0n;
    for (int t = 0; t < TOUT; ++t) {
        cell64_mfma<2><<<big_grid, big_block, 0, stream>>>(d0c, wpd0, dec_b0, c2, c2,
                                                           d0n, 0, 8, d1c, 0, 16);
        cell64_mfma<4><<<big_grid, big_block, 0, stream>>>(d1c, wpd1, dec_b1, c1, c1,
                                                           d1n, 64, 16, nullptr, 0, 0);
        small_cell64<<<dim3(36, NB), 256, 0, stream>>>(d1n, 16, 64, hc, c0,
                                                       dec_w2, dec_b2, hl, c0);
        tcnn_kernel<<<dim3(36, NB), 256, 0, stream>>>(yp, hl, tcnn_w, tcnn_b, ypn, hcn,
                                                      out + (size_t)t * PIX);
        { unsigned short* tmp = d0c; d0c = d0n; d0n = tmp; }
        { unsigned short* tmp = d1c; d1c = d1n; d1n = tmp; }
        { float* tmp = yp; yp = ypn; ypn = tmp; }
        { float* tmp = hc; hc = hcn; hcn = tmp; }
    }
}

// Round 4
// 2084.200 us; speedup vs baseline: 6.7639x; 1.0392x over previous
//
#include <hip/hip_runtime.h>

// WeatherModel: ConvLSTM encoder-decoder with attention.
// Big ConvLSTM cells + attention e-conv via bf16 MFMA implicit GEMM.
// B=4, T_IN=10, T_OUT=5, D=5, M=N=96, H1=64, ATTN=32, SEL=0.

#define PIX  9216
#define NB   4
#define TIN  10
#define TOUT 5
#define ND   5
#define HID  64

typedef __attribute__((ext_vector_type(8))) short bf16x8;
typedef __attribute__((ext_vector_type(4))) float f32x4;

__device__ __forceinline__ float sigmf_(float x) { return 1.0f / (1.0f + __expf(-x)); }
__device__ __forceinline__ float tanhf_(float x) { return 1.0f - 2.0f / (__expf(2.0f * x) + 1.0f); }
__device__ __forceinline__ unsigned short f2bf(float f) {
    unsigned u = __float_as_uint(f);
    unsigned r = u + 0x7FFFu + ((u >> 16) & 1u);
    return (unsigned short)(r >> 16);
}
__device__ __forceinline__ float bf2f(unsigned short u) {
    return __uint_as_float(((unsigned)u) << 16);
}

// ---------------------------------------------------------------------------
// Big ConvLSTM cell, implicit-GEMM MFMA.
// Wave wv owns oc sub-block wv*16 within EACH gate (all 4 gates in-register)
// -> no LDS gate exchange. Double-buffered staging, 1 barrier per cin-chunk.
// Grid: (2, 96, NB) = 768 blocks; block = 4 waves; px tile 48.
// ---------------------------------------------------------------------------
template <int NCH>
__global__ void __launch_bounds__(256, 3)
cell64_mfma(const unsigned short* __restrict__ inP,
            const unsigned short* __restrict__ wP,
            const float* __restrict__ bias,
            const float* cprev, float* cout,
            unsigned short* __restrict__ d1, int d1_coff, int d1_ncg,
            unsigned short* __restrict__ d2, int d2_coff, int d2_ncg)
{
    __shared__ __align__(16) char smem[2][9600];   // [pr 150][4 slots][16B], dbuf
    const int lane = threadIdx.x;
    const int wv   = threadIdx.y;
    const int tid  = wv * 64 + lane;
    const int xh = blockIdx.x, y = blockIdx.y, b = blockIdx.z;
    const int x0 = xh * 48;
    const int l15 = lane & 15, l4 = lane >> 4;
    const int NCG = NCH * 4;

    const int scg  = tid & 3;                      // staging: cg slot
    const int spr0 = tid >> 2;                     // staging: 0..63

    auto stage = [&](char* buf, int cc) {
#pragma unroll
        for (int i = 0; i < 3; ++i) {
            int pr = spr0 + i * 64;                // < 150
            if (i == 2 && pr >= 150) break;
            int r = (pr >= 100) ? 2 : (pr >= 50 ? 1 : 0);
            int p = pr - r * 50;
            int gy = y - 1 + r, gx = x0 - 1 + p;
            uint4 v = make_uint4(0u, 0u, 0u, 0u);
            if ((unsigned)gy < 96u && (unsigned)gx < 96u)
                v = *(const uint4*)(inP + (((size_t)(b * NCG + cc * 4 + scg) * 9216
                                            + gy * 96 + gx) << 3));
            int slot = scg ^ ((p >> 1) & 3);
            *(uint4*)(buf + pr * 64 + slot * 16) = v;
        }
    };

    f32x4 acc[4][3] = {};                          // [gate][px frag]

    stage((char*)smem[0], 0);
    for (int cc = 0; cc < NCH; ++cc) {
        __syncthreads();                           // staging(cc) done; reads(cc-1) done
        if (cc + 1 < NCH) stage((char*)smem[(cc + 1) & 1], cc + 1);
        const char* buf = (const char*)smem[cc & 1];
#pragma unroll
        for (int ky = 0; ky < 3; ++ky) {
#pragma unroll
            for (int kx = 0; kx < 3; ++kx) {
                const int tap = ky * 3 + kx;
                bf16x8 af[4];
#pragma unroll
                for (int g = 0; g < 4; ++g)
                    af[g] = *(const bf16x8*)(wP
                        + ((size_t)(tap * NCH + cc) * 256 + g * 64 + wv * 16 + l15) * 32 + l4 * 8);
                bf16x8 bk[3];
#pragma unroll
                for (int k = 0; k < 3; ++k) {
                    int p = k * 16 + kx + l15;
                    int slot = l4 ^ ((p >> 1) & 3);
                    bk[k] = *(const bf16x8*)(buf + (ky * 50 + p) * 64 + slot * 16);
                }
#pragma unroll
                for (int g = 0; g < 4; ++g)
#pragma unroll
                    for (int k = 0; k < 3; ++k)
                        acc[g][k] = __builtin_amdgcn_mfma_f32_16x16x32_bf16(
                            af[g], bk[k], acc[g][k], 0, 0, 0);
            }
        }
    }

    // in-register epilogue: thread owns hc = wv*16 + l4*4 + r, px = k*16 + l15
#pragma unroll
    for (int r = 0; r < 4; ++r) {
        int hc = wv * 16 + l4 * 4 + r;
        float bi = bias[hc], bff = bias[64 + hc];
        float bo = bias[128 + hc], bg = bias[192 + hc];
#pragma unroll
        for (int k = 0; k < 3; ++k) {
            int px = k * 16 + l15;
            int gpix = y * 96 + x0 + px;
            float ii = sigmf_(acc[0][k][r] + bi);
            float ff = sigmf_(acc[1][k][r] + bff);
            float oo = sigmf_(acc[2][k][r] + bo);
            float gg = tanhf_(acc[3][k][r] + bg);
            int cidx = (b * HID + hc) * 9216 + gpix;
            float cn = ff * cprev[cidx] + ii * gg;
            cout[cidx] = cn;
            unsigned short hb = f2bf(oo * tanhf_(cn));
            int ch1 = d1_coff + hc;
            d1[((size_t)(b * d1_ncg + (ch1 >> 3)) * 9216 + gpix) * 8 + (ch1 & 7)] = hb;
            if (d2) {
                int ch2 = d2_coff + hc;
                d2[((size_t)(b * d2_ncg + (ch2 >> 3)) * 9216 + gpix) * 8 + (ch2 & 7)] = hb;
            }
        }
    }
}

__global__ void wpack_kernel(const float* __restrict__ w, unsigned short* __restrict__ wp,
                             int WCIN, int NCH, int coff, int climit)
{
    int idx = blockIdx.x * 256 + threadIdx.x;
    int total = 9 * NCH * 256 * 32;
    if (idx >= total) return;
    int k = idx & 31;
    int oc = (idx >> 5) & 255;
    int rest = idx >> 13;
    int cc = rest % NCH, tap = rest / NCH;
    int c = cc * 32 + k;
    float v = 0.0f;
    if (c < climit) v = w[(oc * WCIN + (c + coff)) * 9 + tap];
    wp[idx] = f2bf(v);
}

// ---------------------------------------------------------------------------
// Small ConvLSTM cells (hidden=1): thread per (px, gate), wave-uniform gate.
// Block 256 = 64 px x 4 gates; grid (144, NB).
// ---------------------------------------------------------------------------
__global__ void __launch_bounds__(256)
small_cell5(const float* __restrict__ xs_t,
            const float* __restrict__ hprev, const float* cprev,
            const float* __restrict__ w, const float* __restrict__ bias,
            float* __restrict__ hout, float* cout,
            unsigned short* __restrict__ pk, int ncg)
{
    __shared__ float z[4][64];
    const int pxl = threadIdx.x & 63, gate = threadIdx.x >> 6;
    const int p = blockIdx.x * 64 + pxl, bb = blockIdx.y;
    const int y = p / 96, x = p - y * 96;
    float acc = bias[gate];
#pragma unroll
    for (int cin = 0; cin < 6; ++cin) {
        const float* src = (cin < 5) ? (xs_t + (bb * TIN * ND + cin) * PIX)
                                     : (hprev + bb * PIX);
        const float* wp = w + (gate * 6 + cin) * 9;
#pragma unroll
        for (int ky = 0; ky < 3; ++ky) {
            int gy = y + ky - 1;
            if ((unsigned)gy >= 96u) continue;
#pragma unroll
            for (int kx = 0; kx < 3; ++kx) {
                int gx = x + kx - 1;
                if ((unsigned)gx >= 96u) continue;
                acc = fmaf(wp[ky * 3 + kx], src[gy * 96 + gx], acc);
            }
        }
    }
    z[gate][pxl] = acc;
    __syncthreads();
    if (threadIdx.x < 64) {
        int pp = blockIdx.x * 64 + threadIdx.x;
        int idx = bb * PIX + pp;
        float cn = sigmf_(z[1][threadIdx.x]) * cprev[idx]
                 + sigmf_(z[0][threadIdx.x]) * tanhf_(z[3][threadIdx.x]);
        cout[idx] = cn;
        float h = sigmf_(z[2][threadIdx.x]) * tanhf_(cn);
        hout[idx] = h;
        pk[((size_t)(bb * ncg) * 9216 + pp) * 8] = f2bf(h);
    }
}

// dec2 layer: 64 packed bf16 cin (cg base) + 1 float hprev cin.
__global__ void __launch_bounds__(256)
small_cell64(const unsigned short* __restrict__ xin, int ncg, int cgbase,
             const float* __restrict__ hprev, const float* cprev,
             const float* __restrict__ w, const float* __restrict__ bias,
             float* __restrict__ hout, float* cout)
{
    __shared__ float z[4][64];
    const int pxl = threadIdx.x & 63, gate = threadIdx.x >> 6;
    const int p = blockIdx.x * 64 + pxl, bb = blockIdx.y;
    const int y = p / 96, x = p - y * 96;
    float acc = bias[gate];
    const float* wg = w + (size_t)gate * 65 * 9;
#pragma unroll
    for (int ky = 0; ky < 3; ++ky) {
        int gy = y + ky - 1;
        if ((unsigned)gy >= 96u) continue;
#pragma unroll
        for (int kx = 0; kx < 3; ++kx) {
            int gx = x + kx - 1;
            if ((unsigned)gx >= 96u) continue;
            int np = gy * 96 + gx;
            const float* wp = wg + ky * 3 + kx;
#pragma unroll
            for (int grp = 0; grp < 8; ++grp) {
                bf16x8 v = *(const bf16x8*)(xin
                    + ((size_t)(bb * ncg + cgbase + grp) * 9216 + np) * 8);
#pragma unroll
                for (int j = 0; j < 8; ++j)
                    acc = fmaf(wp[(grp * 8 + j) * 9], bf2f((unsigned short)v[j]), acc);
            }
            acc = fmaf(wp[64 * 9], hprev[bb * PIX + np], acc);
        }
    }
    z[gate][pxl] = acc;
    __syncthreads();
    if (threadIdx.x < 64) {
        int pp = blockIdx.x * 64 + threadIdx.x;
        int idx = bb * PIX + pp;
        float cn = sigmf_(z[1][threadIdx.x]) * cprev[idx]
                 + sigmf_(z[0][threadIdx.x]) * tanhf_(z[3][threadIdx.x]);
        cout[idx] = cn;
        hout[idx] = sigmf_(z[2][threadIdx.x]) * tanhf_(cn);
    }
}

// ---------------------------------------------------------------------------
// Attention, MFMA edition (validated round 2).
// ---------------------------------------------------------------------------
__global__ void pack_wi_kernel(const float* __restrict__ wi, unsigned short* __restrict__ wiP)
{
    int idx = blockIdx.x * 256 + threadIdx.x;
    if (idx >= 5120) return;
    int kl = idx & 31, oc = (idx >> 5) & 31, j = idx >> 10;
    int tappos = kl >> 4, ch = kl & 15;
    int tap = 2 * j + tappos;
    float v = 0.0f;
    if (tap < 9 && ch < 10) v = wi[(oc * TIN + ch) * 9 + tap];
    wiP[idx] = f2bf(v);
}

__global__ void hidE_kernel(const float* __restrict__ h0, const float* __restrict__ c0,
                            const float* __restrict__ wh, const float* __restrict__ bh,
                            const float* __restrict__ bi, float* __restrict__ heP)
{
    int idx = blockIdx.x * 256 + threadIdx.x;
    int bb = blockIdx.y;
    int cg = idx & 3, p = idx >> 2;
    int y = p / 96, x = p - y * 96;
    float acc[8];
#pragma unroll
    for (int j = 0; j < 8; ++j) acc[j] = bi[cg * 8 + j] + bh[cg * 8 + j];
#pragma unroll
    for (int cin = 0; cin < 2; ++cin) {
        const float* src = (cin == 0 ? h0 : c0) + bb * PIX;
#pragma unroll
        for (int ky = 0; ky < 3; ++ky) {
            int gy = y + ky - 1;
            if ((unsigned)gy >= 96u) continue;
#pragma unroll
            for (int kx = 0; kx < 3; ++kx) {
                int gx = x + kx - 1;
                if ((unsigned)gx >= 96u) continue;
                float v = src[gy * 96 + gx];
#pragma unroll
                for (int j = 0; j < 8; ++j)
                    acc[j] = fmaf(wh[((cg * 8 + j) * 2 + cin) * 9 + ky * 3 + kx], v, acc[j]);
            }
        }
    }
    float* dst = heP + ((size_t)(bb * PIX) + p) * 32 + cg * 8;
    *(float4*)dst = make_float4(acc[0], acc[1], acc[2], acc[3]);
    *(float4*)(dst + 4) = make_float4(acc[4], acc[5], acc[6], acc[7]);
}

__global__ void __launch_bounds__(256)
attn_e_mfma(const unsigned short* __restrict__ xsp, const unsigned short* __restrict__ wiP,
            const float* __restrict__ heP, unsigned short* __restrict__ eP)
{
    const int lane = threadIdx.x, wvid = threadIdx.y;
    const int tile = blockIdx.x, k = blockIdx.y, bb = blockIdx.z;
    const int l15 = lane & 15, l4 = lane >> 4;

    bf16x8 af[5][2];
#pragma unroll
    for (int j = 0; j < 5; ++j)
#pragma unroll
        for (int m = 0; m < 2; ++m)
            af[j][m] = *(const bf16x8*)(wiP + ((size_t)(j * 32 + m * 16 + l15)) * 32 + l4 * 8);

    const unsigned short* xb = xsp + (size_t)(bb * ND + k) * PIX * 16;
    const int p0 = tile * 256 + wvid * 64;

    f32x4 acc[4][2] = {};
#pragma unroll
    for (int nf = 0; nf < 4; ++nf) {
        int p = p0 + nf * 16 + l15;
        int y = p / 96, x = p - y * 96;
#pragma unroll
        for (int j = 0; j < 5; ++j) {
            int tp = 2 * j + (l4 >> 1);
            bf16x8 bk = { 0, 0, 0, 0, 0, 0, 0, 0 };
            if (tp < 9) {
                int gy = y + tp / 3 - 1, gx = x + tp % 3 - 1;
                if ((unsigned)gy < 96u && (unsigned)gx < 96u)
                    bk = *(const bf16x8*)(xb + ((size_t)(gy * 96 + gx)) * 16 + (l4 & 1) * 8);
            }
            acc[nf][0] = __builtin_amdgcn_mfma_f32_16x16x32_bf16(af[j][0], bk, acc[nf][0], 0, 0, 0);
            acc[nf][1] = __builtin_amdgcn_mfma_f32_16x16x32_bf16(af[j][1], bk, acc[nf][1], 0, 0, 0);
        }
    }

#pragma unroll
    for (int nf = 0; nf < 4; ++nf) {
        int p = p0 + nf * 16 + l15;
#pragma unroll
        for (int m = 0; m < 2; ++m) {
            const float4 he = *(const float4*)(heP + ((size_t)(bb * PIX) + p) * 32 + m * 16 + l4 * 4);
            ushort4 o;
            o.x = f2bf(tanhf_(acc[nf][m][0] + he.x));
            o.y = f2bf(tanhf_(acc[nf][m][1] + he.y));
            o.z = f2bf(tanhf_(acc[nf][m][2] + he.z));
            o.w = f2bf(tanhf_(acc[nf][m][3] + he.w));
            *(ushort4*)(eP + ((size_t)(bb * ND + k) * PIX + p) * 32 + m * 16 + l4 * 4) = o;
        }
    }
}

__global__ void __launch_bounds__(256)
attn_alpha(const unsigned short* __restrict__ eP, const float* __restrict__ wvv,
           const float* __restrict__ bv, float* __restrict__ alpha,
           float* __restrict__ partial)
{
    int p = blockIdx.x * 256 + threadIdx.x;
    int k = blockIdx.y, bb = blockIdx.z;
    int y = p / 96, x = p - y * 96;
    const unsigned short* eb = eP + (size_t)(bb * ND + k) * PIX * 32;
    float acc = bv[0];
#pragma unroll
    for (int ky = 0; ky < 3; ++ky) {
        int gy = y + ky - 1;
        if ((unsigned)gy >= 96u) continue;
#pragma unroll
        for (int kx = 0; kx < 3; ++kx) {
            int gx = x + kx - 1;
            if ((unsigned)gx >= 96u) continue;
            int tap = ky * 3 + kx;
            const unsigned short* ee = eb + ((size_t)(gy * 96 + gx)) * 32;
#pragma unroll
            for (int cg = 0; cg < 4; ++cg) {
                bf16x8 ev = *(const bf16x8*)(ee + cg * 8);
#pragma unroll
                for (int jj = 0; jj < 8; ++jj)
                    acc = fmaf(wvv[(cg * 8 + jj) * 9 + tap], bf2f((unsigned short)ev[jj]), acc);
            }
        }
    }
    alpha[(size_t)(bb * ND + k) * PIX + p] = acc;

    __shared__ float s[256];
    s[threadIdx.x] = acc;
    __syncthreads();
    for (int st = 128; st > 0; st >>= 1) {
        if (threadIdx.x < st) s[threadIdx.x] = fmaxf(s[threadIdx.x], s[threadIdx.x + st]);
        __syncthreads();
    }
    if (threadIdx.x == 0) partial[(bb * ND + k) * 36 + blockIdx.x] = s[0];
}

__global__ void redmax2_kernel(const float* __restrict__ partial, int n, float* __restrict__ out)
{
    __shared__ float s[256];
    float m = -1e30f;
    for (int i = threadIdx.x; i < n; i += 256) m = fmaxf(m, partial[i]);
    s[threadIdx.x] = m;
    __syncthreads();
    for (int st = 128; st > 0; st >>= 1) {
        if (threadIdx.x < st) s[threadIdx.x] = fmaxf(s[threadIdx.x], s[threadIdx.x + st]);
        __syncthreads();
    }
    if (threadIdx.x == 0) out[0] = s[0];
}

__global__ void scale_pack_kernel(float* __restrict__ xs, unsigned short* __restrict__ xsp,
                                  const float* __restrict__ alpha, const float* __restrict__ mval)
{
    int idx = blockIdx.x * 256 + threadIdx.x;
    int p = idx % PIX;
    int q = idx / PIX;
    int d = q % ND, bb = q / ND;
    float w = __expf(alpha[idx] - mval[0]);
    unsigned short tmp[16];
#pragma unroll
    for (int t = 0; t < TIN; ++t) {
        size_t xi = ((size_t)(bb * TIN + t) * ND + d) * PIX + p;
        float v = xs[xi] * w;
        xs[xi] = v;
        tmp[t] = f2bf(v);
    }
#pragma unroll
    for (int t = TIN; t < 16; ++t) tmp[t] = 0;
    uint4* dst = (uint4*)(xsp + (size_t)idx * 16);
    dst[0] = *(uint4*)&tmp[0];
    dst[1] = *(uint4*)&tmp[8];
}

__global__ void pack_xsp_kernel(const float* __restrict__ x, unsigned short* __restrict__ xsp)
{
    int idx = blockIdx.x * 256 + threadIdx.x;
    int p = idx % PIX;
    int q = idx / PIX;
    int d = q % ND, bb = q / ND;
    unsigned short tmp[16];
#pragma unroll
    for (int t = 0; t < TIN; ++t)
        tmp[t] = f2bf(x[((size_t)(bb * TIN + t) * ND + d) * PIX + p]);
#pragma unroll
    for (int t = TIN; t < 16; ++t) tmp[t] = 0;
    uint4* dst = (uint4*)(xsp + (size_t)idx * 16);
    dst[0] = *(uint4*)&tmp[0];
    dst[1] = *(uint4*)&tmp[8];
}

// ---------------------------------------------------------------------------
__global__ void tcnn_kernel(const float* __restrict__ yprev, const float* __restrict__ hl,
                            const float* __restrict__ tw, const float* __restrict__ tb,
                            float* __restrict__ ynext, float* __restrict__ hcarry,
                            float* __restrict__ outp)
{
    int p = blockIdx.x * 256 + threadIdx.x;
    int bb = blockIdx.y;
    float acc = tb[0];
#pragma unroll
    for (int cc = 0; cc < TIN; ++cc)
        acc = fmaf(tw[cc], yprev[(bb * TIN + cc) * PIX + p], acc);
    float hv = hl[bb * PIX + p];
    acc = fmaf(tw[TIN], hv, acc);
    float o = fmaxf(acc, 0.0f);
    outp[bb * TOUT * PIX + p] = o;
#pragma unroll
    for (int cc = 0; cc < TIN - 1; ++cc)
        ynext[(bb * TIN + cc) * PIX + p] = yprev[(bb * TIN + cc + 1) * PIX + p];
    ynext[(bb * TIN + 9) * PIX + p] = hv;
    hcarry[bb * PIX + p] = o;
}

__global__ void slice_y_kernel(const float* __restrict__ x, float* __restrict__ yp)
{
    int idx = blockIdx.x * 256 + threadIdx.x;
    int p = idx % PIX;
    int q = idx / PIX;
    yp[idx] = x[(size_t)(q * ND + 0) * PIX + p];
}

// ---------------------------------------------------------------------------
extern "C" void kernel_launch(void* const* d_in, const int* in_sizes, int n_in,
                              void* d_out, int out_size, void* d_ws, size_t ws_size,
                              hipStream_t stream)
{
    const float* x       = (const float*)d_in[0];
    const float* enc_w0  = (const float*)d_in[1];
    const float* enc_b0  = (const float*)d_in[2];
    const float* enc_w1  = (const float*)d_in[3];
    const float* enc_b1  = (const float*)d_in[4];
    const float* enc_w2  = (const float*)d_in[5];
    const float* enc_b2  = (const float*)d_in[6];
    const float* dec_w0  = (const float*)d_in[7];
    const float* dec_b0  = (const float*)d_in[8];
    const float* dec_w1  = (const float*)d_in[9];
    const float* dec_b1  = (const float*)d_in[10];
    const float* dec_w2  = (const float*)d_in[11];
    const float* dec_b2  = (const float*)d_in[12];
    const float* attn_wi = (const float*)d_in[13];
    const float* attn_bi = (const float*)d_in[14];
    const float* attn_wh = (const float*)d_in[15];
    const float* attn_bh = (const float*)d_in[16];
    const float* attn_wv = (const float*)d_in[17];
    const float* attn_bv = (const float*)d_in[18];
    const float* tcnn_w  = (const float*)d_in[19];
    const float* tcnn_b  = (const float*)d_in[20];
    float* out = (float*)d_out;

    char* cur = (char*)d_ws;
    auto alloc = [&](size_t bytes) { char* p = cur; cur += (bytes + 255) & ~(size_t)255; return p; };
    float* xs   = (float*)alloc((size_t)NB * TIN * ND * PIX * 4);
    float* h0a  = (float*)alloc(NB * PIX * 4);
    float* h0b  = (float*)alloc(NB * PIX * 4);
    float* c0   = (float*)alloc(NB * PIX * 4);
    float* hl   = (float*)alloc(NB * PIX * 4);
    float* c1   = (float*)alloc((size_t)NB * HID * PIX * 4);
    float* c2   = (float*)alloc((size_t)NB * HID * PIX * 4);
    float* alp  = (float*)alloc((size_t)NB * ND * PIX * 4);
    float* ypa  = (float*)alloc((size_t)NB * TIN * PIX * 4);
    float* ypb  = (float*)alloc((size_t)NB * TIN * PIX * 4);
    float* partial = (float*)alloc(4096);
    float* mval = (float*)alloc(256);
    const size_t IN1_B = (size_t)NB * 12 * PIX * 8 * 2;
    const size_t IN2_B = (size_t)NB * 16 * PIX * 8 * 2;
    unsigned short* In1a = (unsigned short*)alloc(IN1_B);
    unsigned short* In1b = (unsigned short*)alloc(IN1_B);
    unsigned short* In2a = (unsigned short*)alloc(IN2_B);
    unsigned short* In2b = (unsigned short*)alloc(IN2_B);
    unsigned short* wpe1 = (unsigned short*)alloc((size_t)9 * 3 * 256 * 32 * 2);
    unsigned short* wpe2 = (unsigned short*)alloc((size_t)9 * 4 * 256 * 32 * 2);
    unsigned short* wpd0 = (unsigned short*)alloc((size_t)9 * 2 * 256 * 32 * 2);
    unsigned short* wpd1 = (unsigned short*)alloc((size_t)9 * 4 * 256 * 32 * 2);
    unsigned short* xsp  = (unsigned short*)alloc((size_t)NB * ND * PIX * 16 * 2);
    unsigned short* wiP  = (unsigned short*)alloc(5120 * 2);
    float* heP = (float*)alloc((size_t)NB * PIX * 32 * 4);
    unsigned short* eP = (unsigned short*)alloc((size_t)NB * ND * PIX * 32 * 2);

    hipMemcpyAsync(xs, x, (size_t)NB * TIN * ND * PIX * 4, hipMemcpyDeviceToDevice, stream);
    hipMemsetAsync(h0a, 0, NB * PIX * 4, stream);
    hipMemsetAsync(c0,  0, NB * PIX * 4, stream);
    hipMemsetAsync(c1,  0, (size_t)NB * HID * PIX * 4, stream);
    hipMemsetAsync(c2,  0, (size_t)NB * HID * PIX * 4, stream);
    hipMemsetAsync(In1a, 0, IN1_B, stream);
    hipMemsetAsync(In1b, 0, IN1_B, stream);
    hipMemsetAsync(In2a, 0, IN2_B, stream);
    hipMemsetAsync(In2b, 0, IN2_B, stream);
    slice_y_kernel<<<dim3(1440), 256, 0, stream>>>(x, ypa);

    wpack_kernel<<<dim3(864),  256, 0, stream>>>(enc_w1, wpe1, 65, 3, 0, 65);
    wpack_kernel<<<dim3(1152), 256, 0, stream>>>(enc_w2, wpe2, 128, 4, 0, 128);
    wpack_kernel<<<dim3(576),  256, 0, stream>>>(dec_w0, wpd0, 65, 2, 1, 64);
    wpack_kernel<<<dim3(1152), 256, 0, stream>>>(dec_w1, wpd1, 128, 4, 0, 128);
    pack_wi_kernel<<<dim3(20), 256, 0, stream>>>(attn_wi, wiP);
    pack_xsp_kernel<<<dim3(720), 256, 0, stream>>>(x, xsp);

    dim3 big_grid(2, 96, NB), big_block(64, 4);
    dim3 attn_block(64, 4);
    float *h0 = h0a, *h0n = h0b;
    unsigned short *i1c = In1a, *i1n = In1b, *i2c = In2a, *i2n = In2b;

    // ---------------- encoder ----------------
    for (int t = 0; t < TIN; ++t) {
        hidE_kernel<<<dim3(144, NB), 256, 0, stream>>>(h0, c0, attn_wh, attn_bh, attn_bi, heP);
        attn_e_mfma<<<dim3(36, ND, NB), attn_block, 0, stream>>>(xsp, wiP, heP, eP);
        attn_alpha<<<dim3(36, ND, NB), 256, 0, stream>>>(eP, attn_wv, attn_bv, alp, partial);
        redmax2_kernel<<<dim3(1), 256, 0, stream>>>(partial, 720, mval);
        scale_pack_kernel<<<dim3(720), 256, 0, stream>>>(xs, xsp, alp, mval);

        small_cell5<<<dim3(144, NB), 256, 0, stream>>>(xs + (size_t)t * ND * PIX, h0, c0,
                                                       enc_w0, enc_b0, h0n, c0, i1c, 12);
        { float* tmp = h0; h0 = h0n; h0n = tmp; }

        unsigned short* e1d1 = (t < TIN - 1) ? i1n : In2a;
        int e1o = (t < TIN - 1) ? 1 : 64;
        int e1n = (t < TIN - 1) ? 12 : 16;
        cell64_mfma<3><<<big_grid, big_block, 0, stream>>>(i1c, wpe1, enc_b1, c1, c1,
                                                           e1d1, e1o, e1n, i2c, 0, 16);
        unsigned short* e2d1 = (t < TIN - 1) ? i2n : In1a;
        int e2o = (t < TIN - 1) ? 64 : 0;
        int e2n = (t < TIN - 1) ? 16 : 8;
        cell64_mfma<4><<<big_grid, big_block, 0, stream>>>(i2c, wpe2, enc_b2, c2, c2,
                                                           e2d1, e2o, e2n, nullptr, 0, 0);
        { unsigned short* tmp = i1c; i1c = i1n; i1n = tmp; }
        { unsigned short* tmp = i2c; i2c = i2n; i2n = tmp; }
    }

    // ---------------- decoder ----------------
    unsigned short *d0c = In1a, *d0n = In1b, *d1c = In2a, *d1n = In2b;
    float *yp = ypa, *ypn = ypb, *hc = h0, *hcn = h0n;
    for (int t = 0; t < TOUT; ++t) {
        cell64_mfma<2><<<big_grid, big_block, 0, stream>>>(d0c, wpd0, dec_b0, c2, c2,
                                                           d0n, 0, 8, d1c, 0, 16);
        cell64_mfma<4><<<big_grid, big_block, 0, stream>>>(d1c, wpd1, dec_b1, c1, c1,
                                                           d1n, 64, 16, nullptr, 0, 0);
        small_cell64<<<dim3(144, NB), 256, 0, stream>>>(d1n, 16, 8, hc, c0,
                                                        dec_w2, dec_b2, hl, c0);
        tcnn_kernel<<<dim3(36, NB), 256, 0, stream>>>(yp, hl, tcnn_w, tcnn_b, ypn, hcn,
                                                      out + (size_t)t * PIX);
        { unsigned short* tmp = d0c; d0c = d0n; d0n = tmp; }
        { unsigned short* tmp = d1c; d1c = d1n; d1n = tmp; }
        { float* tmp = yp; yp = ypn; ypn = tmp; }
        { float* tmp = hc; hc = hcn; hcn = tmp; }
    }
}